// Round 1
// baseline (362.644 us; speedup 1.0000x reference)
//
#include <hip/hip_runtime.h>
#include <hip/hip_bf16.h>
#include <math.h>

#define N_ 768
#define M_ 768
#define D_ 128
#define H_ 8
#define DH_ 16
#define FF_ 512

typedef float f32x4 __attribute__((ext_vector_type(4)));
typedef short bf16x8 __attribute__((ext_vector_type(8)));

__device__ __forceinline__ float siluf(float x) { return x / (1.0f + __expf(-x)); }

__device__ __forceinline__ unsigned short f2bf(float x) {
    unsigned int u = __float_as_uint(x);
    unsigned int r = (u + 0x7fffu + ((u >> 16) & 1u)) >> 16;
    return (unsigned short)r;
}

// ---------------- LayerNorm over D=128, one wave per row ----------------
__global__ __launch_bounds__(64) void k_ln(const float* __restrict__ src,
                                           const float* __restrict__ g,
                                           const float* __restrict__ b,
                                           float* __restrict__ dst) {
    int row = blockIdx.x, lane = threadIdx.x;
    const float* x = src + row * D_;
    float x0 = x[lane], x1 = x[lane + 64];
    float s = x0 + x1;
#pragma unroll
    for (int o = 32; o > 0; o >>= 1) s += __shfl_xor(s, o);
    float mu = s * (1.f / 128.f);
    float d0 = x0 - mu, d1 = x1 - mu;
    float v2 = d0 * d0 + d1 * d1;
#pragma unroll
    for (int o = 32; o > 0; o >>= 1) v2 += __shfl_xor(v2, o);
    float inv = rsqrtf(v2 * (1.f / 128.f) + 1e-5f);
    float* out = dst + row * D_;
    out[lane] = d0 * inv * g[lane] + b[lane];
    out[lane + 64] = d1 * inv * g[lane + 64] + b[lane + 64];
}

// ---------------- q/k/v projections: blockIdx.y selects which ----------------
__global__ __launch_bounds__(128) void k_qkv(const float* __restrict__ qh,
                                             const float* __restrict__ rh,
                                             const float* __restrict__ h_r,
                                             const float* __restrict__ Wq, const float* __restrict__ bq,
                                             const float* __restrict__ Wk, const float* __restrict__ bk,
                                             const float* __restrict__ Wv, const float* __restrict__ bv,
                                             float* __restrict__ q, float* __restrict__ k, float* __restrict__ v) {
    int row = blockIdx.x, which = blockIdx.y, j = threadIdx.x;
    const float* in; const float* W; const float* b; float* out;
    if (which == 0) { in = qh + row * D_; W = Wq; b = bq; out = q + row * D_; }
    else if (which == 1) { in = rh + row * D_; W = Wk; b = bk; out = k + row * D_; }
    else { in = h_r + row * D_; W = Wv; b = bv; out = v + row * D_; }
    __shared__ float xs[D_];
    xs[j] = in[j];
    __syncthreads();
    const float4* Wr = (const float4*)(W + j * D_);
    float acc = 0.f;
#pragma unroll
    for (int i = 0; i < 32; i++) {
        float4 w = Wr[i];
        acc += w.x * xs[4 * i] + w.y * xs[4 * i + 1] + w.z * xs[4 * i + 2] + w.w * xs[4 * i + 3];
    }
    out[j] = acc + b[j];
}

// ---------------- attention: one block per n, loop heads ----------------
__global__ __launch_bounds__(256) void k_attn(const float* __restrict__ q,
                                              const float* __restrict__ k,
                                              const float* __restrict__ v,
                                              const float* __restrict__ k_null,
                                              const float* __restrict__ v_null,
                                              const float* __restrict__ b_null,
                                              float* __restrict__ a_s,
                                              float* __restrict__ gate,
                                              float* __restrict__ msg) {
    int n = blockIdx.x, t = threadIdx.x;
    int lane = t & 63, wid = t >> 6;
    __shared__ float sc[M_];       // a-values for current head
    __shared__ float as_l[M_];     // mean-over-heads accumulator
    __shared__ float redm[4], reds[4];
    __shared__ float part[256];
#pragma unroll
    for (int c = 0; c < 3; c++) as_l[t + 256 * c] = 0.f;
    float gate_acc = 0.f;
    const float inv = 0.25f;  // 1/sqrt(16)

    for (int h = 0; h < H_; h++) {
        float qr[DH_];
        const float* qp = q + n * D_ + h * DH_;
#pragma unroll
        for (int d = 0; d < DH_; d++) qr[d] = qp[d];
        float ll[3]; float lmax = -3.4e38f;
#pragma unroll
        for (int c = 0; c < 3; c++) {
            int m = t + 256 * c;
            const float* kp = k + m * D_ + h * DH_;
            float acc = 0.f;
#pragma unroll
            for (int d = 0; d < DH_; d++) acc += qr[d] * kp[d];
            acc *= inv;
            ll[c] = acc;
            lmax = fmaxf(lmax, acc);
        }
        __syncthreads();  // protect sc/part/red from previous head
        // block max: wave shuffle + 4-entry LDS combine
#pragma unroll
        for (int o = 32; o > 0; o >>= 1) lmax = fmaxf(lmax, __shfl_xor(lmax, o));
        if (lane == 0) redm[wid] = lmax;
        __syncthreads();
        float mx = fmaxf(fmaxf(redm[0], redm[1]), fmaxf(redm[2], redm[3]));
        float es = 0.f;
#pragma unroll
        for (int c = 0; c < 3; c++) es += __expf(ll[c] - mx);
#pragma unroll
        for (int o = 32; o > 0; o >>= 1) es += __shfl_xor(es, o);
        if (lane == 0) reds[wid] = es;
        __syncthreads();
        float sum = reds[0] + reds[1] + reds[2] + reds[3];

        float lnull;
        {
            const float* kp = k_null + h * DH_;
            float acc = 0.f;
#pragma unroll
            for (int d = 0; d < DH_; d++) acc += qr[d] * kp[d];
            lnull = acc * inv + b_null[h];
        }
        float lse_real = mx + __logf(sum + 1e-9f);
        float m2 = fmaxf(lse_real, lnull);
        float lse_all = m2 + __logf(__expf(lse_real - m2) + __expf(lnull - m2));
        float a_null = __expf(lnull - lse_all);
        gate_acc += fminf(1.f, __expf(lse_real - lse_all));
#pragma unroll
        for (int c = 0; c < 3; c++) {
            int m = t + 256 * c;
            float a = __expf(ll[c] - lse_all);
            sc[m] = a;
            as_l[m] += 0.125f * a;
        }
        __syncthreads();
        // msg: 16 dims x 16 groups of 48 m's
        int d = t & 15, gI = t >> 4;
        float p = 0.f;
        int mbase = gI * 48;
        for (int i = 0; i < 48; i++) {
            int m = mbase + i;
            p += sc[m] * v[m * D_ + h * DH_ + d];
        }
        part[t] = p;
        __syncthreads();
        if (t < DH_) {
            float s3 = 0.f;
#pragma unroll
            for (int g2 = 0; g2 < 16; g2++) s3 += part[g2 * 16 + t];
            msg[n * D_ + h * DH_ + t] = s3 + a_null * v_null[h * DH_ + t];
        }
    }
    __syncthreads();
#pragma unroll
    for (int c = 0; c < 3; c++) a_s[n * M_ + t + 256 * c] = as_l[t + 256 * c];
    if (t == 0) gate[n] = gate_acc * 0.125f;
}

// ---------------- out-proj + residual ----------------
__global__ __launch_bounds__(128) void k_outproj(const float* __restrict__ h_q,
                                                 const float* __restrict__ msg,
                                                 const float* __restrict__ Wo,
                                                 const float* __restrict__ bop,
                                                 float* __restrict__ h_mid) {
    int row = blockIdx.x, j = threadIdx.x;
    __shared__ float xs[D_];
    xs[j] = msg[row * D_ + j];
    __syncthreads();
    const float4* Wr = (const float4*)(Wo + j * D_);
    float acc = 0.f;
#pragma unroll
    for (int i = 0; i < 32; i++) {
        float4 w = Wr[i];
        acc += w.x * xs[4 * i] + w.y * xs[4 * i + 1] + w.z * xs[4 * i + 2] + w.w * xs[4 * i + 3];
    }
    h_mid[row * D_ + j] = h_q[row * D_ + j] + acc + bop[j];
}

// ---------------- FFN layer 1 with silu ----------------
__global__ __launch_bounds__(256) void k_ffn1(const float* __restrict__ tln,
                                              const float* __restrict__ W1,
                                              const float* __restrict__ b1,
                                              float* __restrict__ ffh) {
    int row = blockIdx.x, t = threadIdx.x;
    __shared__ float xs[D_];
    if (t < 128) xs[t] = tln[row * D_ + t];
    __syncthreads();
#pragma unroll
    for (int jj = 0; jj < 2; jj++) {
        int j = t + 256 * jj;
        const float4* Wr = (const float4*)(W1 + j * D_);
        float acc = 0.f;
#pragma unroll
        for (int i = 0; i < 32; i++) {
            float4 w = Wr[i];
            acc += w.x * xs[4 * i] + w.y * xs[4 * i + 1] + w.z * xs[4 * i + 2] + w.w * xs[4 * i + 3];
        }
        ffh[row * FF_ + j] = siluf(acc + b1[j]);
    }
}

// ---------------- FFN layer 2 + residual -> d_out (h part) ----------------
__global__ __launch_bounds__(128) void k_ffn2(const float* __restrict__ h_mid,
                                              const float* __restrict__ ffh,
                                              const float* __restrict__ W2,
                                              const float* __restrict__ b2,
                                              float* __restrict__ h_out) {
    int row = blockIdx.x, j = threadIdx.x;
    __shared__ float xs[FF_];
#pragma unroll
    for (int c = 0; c < 4; c++) xs[j + 128 * c] = ffh[row * FF_ + j + 128 * c];
    __syncthreads();
    const float4* Wr = (const float4*)(W2 + j * FF_);
    float acc = 0.f;
#pragma unroll
    for (int i = 0; i < 128; i++) {
        float4 w = Wr[i];
        acc += w.x * xs[4 * i] + w.y * xs[4 * i + 1] + w.z * xs[4 * i + 2] + w.w * xs[4 * i + 3];
    }
    h_out[row * D_ + j] = h_mid[row * D_ + j] + acc + b2[j];
}

// ---------------- edge-MLP layer-1 precompute: Aq, Br(+be1), w1r ----------------
__global__ __launch_bounds__(128) void k_pre(const float* __restrict__ qh_new,
                                             const float* __restrict__ rh,
                                             const float* __restrict__ We1,
                                             const float* __restrict__ be1,
                                             float* __restrict__ Aq,
                                             float* __restrict__ Br,
                                             float* __restrict__ w1r) {
    int row = blockIdx.x, o = threadIdx.x;
    __shared__ float xs[D_];
    const float* in; float* out; int off;
    if (row < N_) { in = qh_new + row * D_; out = Aq + row * D_; off = 0; }
    else { in = rh + (row - N_) * D_; out = Br + (row - N_) * D_; off = 128; }
    xs[o] = in[o];
    __syncthreads();
    const float* Wr = We1 + o * 257 + off;
    float acc = 0.f;
#pragma unroll 8
    for (int i = 0; i < 128; i++) acc += Wr[i] * xs[i];
    out[o] = acc + (off ? be1[o] : 0.f);
    if (row == 0) w1r[o] = We1[o * 257 + 256];
}

// ---------------- We2 -> bf16 ----------------
__global__ __launch_bounds__(256) void k_cvt(const float* __restrict__ We2,
                                             unsigned short* __restrict__ We2b) {
    int i = blockIdx.x * 256 + threadIdx.x;
    We2b[i] = f2bf(We2[i]);
}

// ---------------- pair kernel: per-n block, MFMA layer-2, dx accumulate ----------------
__global__ __launch_bounds__(128) void k_pair(const float* __restrict__ x_q,
                                              const float* __restrict__ x_r,
                                              const float* __restrict__ Aq,
                                              const float* __restrict__ Br,
                                              const float* __restrict__ w1r,
                                              const float* __restrict__ be2,
                                              const float* __restrict__ Ws,
                                              const unsigned short* __restrict__ We2b,
                                              const float* __restrict__ a_s,
                                              const float* __restrict__ gate,
                                              float* __restrict__ x_out) {
    int n = blockIdx.x;
    int t = threadIdx.x;
    int w = t >> 6;
    int lane = t & 63;
    int col = lane & 15;   // A-row (pair) for writes, B/D col for MFMA
    int kg = lane >> 4;    // k-group

    __shared__ float xr_l[M_ * 3];
    __shared__ float as_l[M_];
    __shared__ float Aq_l[D_];
    __shared__ float w1r_l[D_];
    __shared__ float be2_l[D_];
    __shared__ float Ws_l[D_];
    __shared__ float dxw[2][3];

    for (int i = t; i < M_ * 3; i += 128) xr_l[i] = x_r[i];
    for (int i = t; i < M_; i += 128) as_l[i] = a_s[n * M_ + i];
    Aq_l[t] = Aq[n * D_ + t];
    w1r_l[t] = w1r[t];
    be2_l[t] = be2[t];
    Ws_l[t] = Ws[t];
    __syncthreads();

    // register-resident B fragments: B[o][p] = We2[p][o]
    bf16x8 bf[8][4];
#pragma unroll
    for (int pt = 0; pt < 8; pt++)
#pragma unroll
        for (int kt = 0; kt < 4; kt++)
            bf[pt][kt] = *reinterpret_cast<const bf16x8*>(We2b + (pt * 16 + col) * D_ + kt * 32 + kg * 8);

    float xq0 = x_q[n * 3 + 0], xq1 = x_q[n * 3 + 1], xq2 = x_q[n * 3 + 2];
    float dxa = 0.f, dya = 0.f, dza = 0.f;

    for (int it = 0; it < 24; it++) {
        int mb = (it * 2 + w) * 16;
        int pm = mb + col;
        float d0 = xq0 - xr_l[pm * 3], d1 = xq1 - xr_l[pm * 3 + 1], d2 = xq2 - xr_l[pm * 3 + 2];
        float radial = d0 * d0 + d1 * d1 + d2 * d2;

        bf16x8 af[4];
#pragma unroll
        for (int kt = 0; kt < 4; kt++) {
            int ob = kt * 32 + kg * 8;
            const float4* brp = reinterpret_cast<const float4*>(Br + pm * D_ + ob);
            float4 b0 = brp[0], b1 = brp[1];
            float hv[8];
            hv[0] = Aq_l[ob + 0] + b0.x + radial * w1r_l[ob + 0];
            hv[1] = Aq_l[ob + 1] + b0.y + radial * w1r_l[ob + 1];
            hv[2] = Aq_l[ob + 2] + b0.z + radial * w1r_l[ob + 2];
            hv[3] = Aq_l[ob + 3] + b0.w + radial * w1r_l[ob + 3];
            hv[4] = Aq_l[ob + 4] + b1.x + radial * w1r_l[ob + 4];
            hv[5] = Aq_l[ob + 5] + b1.y + radial * w1r_l[ob + 5];
            hv[6] = Aq_l[ob + 6] + b1.z + radial * w1r_l[ob + 6];
            hv[7] = Aq_l[ob + 7] + b1.w + radial * w1r_l[ob + 7];
#pragma unroll
            for (int j = 0; j < 8; j++) af[kt][j] = (short)f2bf(siluf(hv[j]));
        }

        float ssum[4] = {0.f, 0.f, 0.f, 0.f};
#pragma unroll
        for (int pt = 0; pt < 8; pt++) {
            f32x4 acc = {0.f, 0.f, 0.f, 0.f};
#pragma unroll
            for (int kt = 0; kt < 4; kt++)
                acc = __builtin_amdgcn_mfma_f32_16x16x32_bf16(af[kt], bf[pt][kt], acc, 0, 0, 0);
            int p = pt * 16 + col;
            float be = be2_l[p], wsv = Ws_l[p];
#pragma unroll
            for (int r = 0; r < 4; r++) ssum[r] += siluf(acc[r] + be) * wsv;
        }
        // reduce over the 16 cols (p) -> s per pair row kg*4+r
#pragma unroll
        for (int o = 1; o < 16; o <<= 1) {
#pragma unroll
            for (int r = 0; r < 4; r++) ssum[r] += __shfl_xor(ssum[r], o);
        }
        if (col == 0) {
#pragma unroll
            for (int r = 0; r < 4; r++) {
                int m2 = mb + kg * 4 + r;
                float sw = ssum[r] * as_l[m2];
                float e0 = xq0 - xr_l[m2 * 3], e1 = xq1 - xr_l[m2 * 3 + 1], e2 = xq2 - xr_l[m2 * 3 + 2];
                float ir = rsqrtf(e0 * e0 + e1 * e1 + e2 * e2 + 1e-8f);
                dxa += e0 * ir * sw;
                dya += e1 * ir * sw;
                dza += e2 * ir * sw;
            }
        }
    }
#pragma unroll
    for (int o = 1; o < 64; o <<= 1) {
        dxa += __shfl_xor(dxa, o);
        dya += __shfl_xor(dya, o);
        dza += __shfl_xor(dza, o);
    }
    if (lane == 0) { dxw[w][0] = dxa; dxw[w][1] = dya; dxw[w][2] = dza; }
    __syncthreads();
    if (t == 0) {
        float gv = gate[n];
        x_out[n * 3 + 0] = xq0 + (dxw[0][0] + dxw[1][0]) * gv;
        x_out[n * 3 + 1] = xq1 + (dxw[0][1] + dxw[1][1]) * gv;
        x_out[n * 3 + 2] = xq2 + (dxw[0][2] + dxw[1][2]) * gv;
    }
}

extern "C" void kernel_launch(void* const* d_in, const int* in_sizes, int n_in,
                              void* d_out, int out_size, void* d_ws, size_t ws_size,
                              hipStream_t stream) {
    const float* h_q   = (const float*)d_in[0];
    const float* x_q   = (const float*)d_in[1];
    const float* h_r   = (const float*)d_in[2];
    const float* x_r   = (const float*)d_in[3];
    // d_in[4], d_in[5]: masks (all true in this problem) -- unused
    const float* Wq    = (const float*)d_in[6];
    const float* bqp   = (const float*)d_in[7];
    const float* Wk    = (const float*)d_in[8];
    const float* bkp   = (const float*)d_in[9];
    const float* Wv    = (const float*)d_in[10];
    const float* bvp   = (const float*)d_in[11];
    const float* Wo    = (const float*)d_in[12];
    const float* bop   = (const float*)d_in[13];
    const float* g_nq  = (const float*)d_in[14];
    const float* b_nq  = (const float*)d_in[15];
    const float* g_nr  = (const float*)d_in[16];
    const float* b_nr  = (const float*)d_in[17];
    const float* g_ff  = (const float*)d_in[18];
    const float* b_ff  = (const float*)d_in[19];
    const float* W1    = (const float*)d_in[20];
    const float* b1    = (const float*)d_in[21];
    const float* W2    = (const float*)d_in[22];
    const float* b2    = (const float*)d_in[23];
    const float* k_null= (const float*)d_in[24];
    const float* v_null= (const float*)d_in[25];
    const float* b_null= (const float*)d_in[26];
    const float* We1   = (const float*)d_in[27];
    const float* be1   = (const float*)d_in[28];
    const float* We2   = (const float*)d_in[29];
    const float* be2   = (const float*)d_in[30];
    const float* Ws    = (const float*)d_in[31];

    float* ws     = (float*)d_ws;
    float* qh     = ws;                  // N*D
    float* rh     = qh + N_ * D_;        // M*D
    float* q      = rh + M_ * D_;        // N*D
    float* k      = q + N_ * D_;         // M*D
    float* v      = k + M_ * D_;         // M*D
    float* a_s    = v + M_ * D_;         // N*M
    float* gate   = a_s + N_ * M_;       // N
    float* msg    = gate + N_;           // N*D
    float* h_mid  = msg + N_ * D_;       // N*D
    float* t_ln   = h_mid + N_ * D_;     // N*D
    float* ffh    = t_ln + N_ * D_;      // N*FF
    float* qh_new = ffh + N_ * FF_;      // N*D
    float* Aq     = qh_new + N_ * D_;    // N*D
    float* Br     = Aq + N_ * D_;        // M*D
    float* w1r    = Br + M_ * D_;        // D
    unsigned short* We2b = (unsigned short*)(w1r + D_);  // D*D bf16

    float* h_out = (float*)d_out;        // N*D
    float* x_out = h_out + N_ * D_;      // N*3

    k_ln<<<N_, 64, 0, stream>>>(h_q, g_nq, b_nq, qh);
    k_ln<<<M_, 64, 0, stream>>>(h_r, g_nr, b_nr, rh);
    k_cvt<<<64, 256, 0, stream>>>(We2, We2b);
    k_qkv<<<dim3(N_, 3), 128, 0, stream>>>(qh, rh, h_r, Wq, bqp, Wk, bkp, Wv, bvp, q, k, v);
    k_attn<<<N_, 256, 0, stream>>>(q, k, v, k_null, v_null, b_null, a_s, gate, msg);
    k_outproj<<<N_, 128, 0, stream>>>(h_q, msg, Wo, bop, h_mid);
    k_ln<<<N_, 64, 0, stream>>>(h_mid, g_ff, b_ff, t_ln);
    k_ffn1<<<N_, 256, 0, stream>>>(t_ln, W1, b1, ffh);
    k_ffn2<<<N_, 128, 0, stream>>>(h_mid, ffh, W2, b2, h_out);
    k_ln<<<N_, 64, 0, stream>>>(h_out, g_nq, b_nq, qh_new);
    k_pre<<<N_ + M_, 128, 0, stream>>>(qh_new, rh, We1, be1, Aq, Br, w1r);
    k_pair<<<N_, 128, 0, stream>>>(x_q, x_r, Aq, Br, w1r, be2, Ws, We2b, a_s, gate, x_out);
}

// Round 2
// 294.773 us; speedup vs baseline: 1.2302x; 1.2302x over previous
//
#include <hip/hip_runtime.h>
#include <hip/hip_bf16.h>
#include <math.h>

#define N_ 768
#define M_ 768
#define D_ 128
#define H_ 8
#define DH_ 16
#define FF_ 512
#define CH_ 4
#define CM_ 192   // M_/CH_

typedef float f32x4 __attribute__((ext_vector_type(4)));
typedef short bf16x8 __attribute__((ext_vector_type(8)));

__device__ __forceinline__ float siluf(float x) { return x / (1.0f + __expf(-x)); }

__device__ __forceinline__ unsigned short f2bf(float x) {
    unsigned int u = __float_as_uint(x);
    unsigned int r = (u + 0x7fffu + ((u >> 16) & 1u)) >> 16;
    return (unsigned short)r;
}

__device__ __forceinline__ short f2bf_rn(float x) {
    __hip_bfloat16 b = __float2bfloat16(x);
    return (short)*reinterpret_cast<unsigned short*>(&b);
}

// ---------------- LayerNorm over D=128, one wave per row ----------------
__global__ __launch_bounds__(64) void k_ln(const float* __restrict__ src,
                                           const float* __restrict__ g,
                                           const float* __restrict__ b,
                                           float* __restrict__ dst) {
    int row = blockIdx.x, lane = threadIdx.x;
    const float* x = src + row * D_;
    float x0 = x[lane], x1 = x[lane + 64];
    float s = x0 + x1;
#pragma unroll
    for (int o = 32; o > 0; o >>= 1) s += __shfl_xor(s, o);
    float mu = s * (1.f / 128.f);
    float d0 = x0 - mu, d1 = x1 - mu;
    float v2 = d0 * d0 + d1 * d1;
#pragma unroll
    for (int o = 32; o > 0; o >>= 1) v2 += __shfl_xor(v2, o);
    float inv = rsqrtf(v2 * (1.f / 128.f) + 1e-5f);
    float* out = dst + row * D_;
    out[lane] = d0 * inv * g[lane] + b[lane];
    out[lane + 64] = d1 * inv * g[lane + 64] + b[lane + 64];
}

// ---------------- q/k/v projections: blockIdx.y selects which ----------------
__global__ __launch_bounds__(128) void k_qkv(const float* __restrict__ qh,
                                             const float* __restrict__ rh,
                                             const float* __restrict__ h_r,
                                             const float* __restrict__ Wq, const float* __restrict__ bq,
                                             const float* __restrict__ Wk, const float* __restrict__ bk,
                                             const float* __restrict__ Wv, const float* __restrict__ bv,
                                             float* __restrict__ q, float* __restrict__ k, float* __restrict__ v) {
    int row = blockIdx.x, which = blockIdx.y, j = threadIdx.x;
    const float* in; const float* W; const float* b; float* out;
    if (which == 0) { in = qh + row * D_; W = Wq; b = bq; out = q + row * D_; }
    else if (which == 1) { in = rh + row * D_; W = Wk; b = bk; out = k + row * D_; }
    else { in = h_r + row * D_; W = Wv; b = bv; out = v + row * D_; }
    __shared__ float xs[D_];
    xs[j] = in[j];
    __syncthreads();
    const float4* Wr = (const float4*)(W + j * D_);
    float acc = 0.f;
#pragma unroll
    for (int i = 0; i < 32; i++) {
        float4 w = Wr[i];
        acc += w.x * xs[4 * i] + w.y * xs[4 * i + 1] + w.z * xs[4 * i + 2] + w.w * xs[4 * i + 3];
    }
    out[j] = acc + b[j];
}

// ---------------- attention: one block per n, loop heads ----------------
__global__ __launch_bounds__(256) void k_attn(const float* __restrict__ q,
                                              const float* __restrict__ k,
                                              const float* __restrict__ v,
                                              const float* __restrict__ k_null,
                                              const float* __restrict__ v_null,
                                              const float* __restrict__ b_null,
                                              float* __restrict__ a_s,
                                              float* __restrict__ gate,
                                              float* __restrict__ msg) {
    int n = blockIdx.x, t = threadIdx.x;
    int lane = t & 63, wid = t >> 6;
    __shared__ float sc[M_];       // a-values for current head
    __shared__ float as_l[M_];     // mean-over-heads accumulator
    __shared__ float redm[4], reds[4];
    __shared__ float part[256];
#pragma unroll
    for (int c = 0; c < 3; c++) as_l[t + 256 * c] = 0.f;
    float gate_acc = 0.f;
    const float inv = 0.25f;  // 1/sqrt(16)

    for (int h = 0; h < H_; h++) {
        float qr[DH_];
        const float* qp = q + n * D_ + h * DH_;
#pragma unroll
        for (int d = 0; d < DH_; d++) qr[d] = qp[d];
        float ll[3]; float lmax = -3.4e38f;
#pragma unroll
        for (int c = 0; c < 3; c++) {
            int m = t + 256 * c;
            const float* kp = k + m * D_ + h * DH_;
            float acc = 0.f;
#pragma unroll
            for (int d = 0; d < DH_; d++) acc += qr[d] * kp[d];
            acc *= inv;
            ll[c] = acc;
            lmax = fmaxf(lmax, acc);
        }
        __syncthreads();  // protect sc/part/red from previous head
#pragma unroll
        for (int o = 32; o > 0; o >>= 1) lmax = fmaxf(lmax, __shfl_xor(lmax, o));
        if (lane == 0) redm[wid] = lmax;
        __syncthreads();
        float mx = fmaxf(fmaxf(redm[0], redm[1]), fmaxf(redm[2], redm[3]));
        float es = 0.f;
#pragma unroll
        for (int c = 0; c < 3; c++) es += __expf(ll[c] - mx);
#pragma unroll
        for (int o = 32; o > 0; o >>= 1) es += __shfl_xor(es, o);
        if (lane == 0) reds[wid] = es;
        __syncthreads();
        float sum = reds[0] + reds[1] + reds[2] + reds[3];

        float lnull;
        {
            const float* kp = k_null + h * DH_;
            float acc = 0.f;
#pragma unroll
            for (int d = 0; d < DH_; d++) acc += qr[d] * kp[d];
            lnull = acc * inv + b_null[h];
        }
        float lse_real = mx + __logf(sum + 1e-9f);
        float m2 = fmaxf(lse_real, lnull);
        float lse_all = m2 + __logf(__expf(lse_real - m2) + __expf(lnull - m2));
        float a_null = __expf(lnull - lse_all);
        gate_acc += fminf(1.f, __expf(lse_real - lse_all));
#pragma unroll
        for (int c = 0; c < 3; c++) {
            int m = t + 256 * c;
            float a = __expf(ll[c] - lse_all);
            sc[m] = a;
            as_l[m] += 0.125f * a;
        }
        __syncthreads();
        // msg: 16 dims x 16 groups of 48 m's
        int d = t & 15, gI = t >> 4;
        float p = 0.f;
        int mbase = gI * 48;
        for (int i = 0; i < 48; i++) {
            int m = mbase + i;
            p += sc[m] * v[m * D_ + h * DH_ + d];
        }
        part[t] = p;
        __syncthreads();
        if (t < DH_) {
            float s3 = 0.f;
#pragma unroll
            for (int g2 = 0; g2 < 16; g2++) s3 += part[g2 * 16 + t];
            msg[n * D_ + h * DH_ + t] = s3 + a_null * v_null[h * DH_ + t];
        }
    }
    __syncthreads();
#pragma unroll
    for (int c = 0; c < 3; c++) a_s[n * M_ + t + 256 * c] = as_l[t + 256 * c];
    if (t == 0) gate[n] = gate_acc * 0.125f;
}

// ---------------- out-proj + residual ----------------
__global__ __launch_bounds__(128) void k_outproj(const float* __restrict__ h_q,
                                                 const float* __restrict__ msg,
                                                 const float* __restrict__ Wo,
                                                 const float* __restrict__ bop,
                                                 float* __restrict__ h_mid) {
    int row = blockIdx.x, j = threadIdx.x;
    __shared__ float xs[D_];
    xs[j] = msg[row * D_ + j];
    __syncthreads();
    const float4* Wr = (const float4*)(Wo + j * D_);
    float acc = 0.f;
#pragma unroll
    for (int i = 0; i < 32; i++) {
        float4 w = Wr[i];
        acc += w.x * xs[4 * i] + w.y * xs[4 * i + 1] + w.z * xs[4 * i + 2] + w.w * xs[4 * i + 3];
    }
    h_mid[row * D_ + j] = h_q[row * D_ + j] + acc + bop[j];
}

// ---------------- FFN layer 1 with silu ----------------
__global__ __launch_bounds__(256) void k_ffn1(const float* __restrict__ tln,
                                              const float* __restrict__ W1,
                                              const float* __restrict__ b1,
                                              float* __restrict__ ffh) {
    int row = blockIdx.x, t = threadIdx.x;
    __shared__ float xs[D_];
    if (t < 128) xs[t] = tln[row * D_ + t];
    __syncthreads();
#pragma unroll
    for (int jj = 0; jj < 2; jj++) {
        int j = t + 256 * jj;
        const float4* Wr = (const float4*)(W1 + j * D_);
        float acc = 0.f;
#pragma unroll
        for (int i = 0; i < 32; i++) {
            float4 w = Wr[i];
            acc += w.x * xs[4 * i] + w.y * xs[4 * i + 1] + w.z * xs[4 * i + 2] + w.w * xs[4 * i + 3];
        }
        ffh[row * FF_ + j] = siluf(acc + b1[j]);
    }
}

// ---------------- FFN layer 2 + residual -> d_out (h part) ----------------
__global__ __launch_bounds__(128) void k_ffn2(const float* __restrict__ h_mid,
                                              const float* __restrict__ ffh,
                                              const float* __restrict__ W2,
                                              const float* __restrict__ b2,
                                              float* __restrict__ h_out) {
    int row = blockIdx.x, j = threadIdx.x;
    __shared__ float xs[FF_];
#pragma unroll
    for (int c = 0; c < 4; c++) xs[j + 128 * c] = ffh[row * FF_ + j + 128 * c];
    __syncthreads();
    const float4* Wr = (const float4*)(W2 + j * FF_);
    float acc = 0.f;
#pragma unroll
    for (int i = 0; i < 128; i++) {
        float4 w = Wr[i];
        acc += w.x * xs[4 * i] + w.y * xs[4 * i + 1] + w.z * xs[4 * i + 2] + w.w * xs[4 * i + 3];
    }
    h_out[row * D_ + j] = h_mid[row * D_ + j] + acc + b2[j];
}

// ---------------- edge-MLP layer-1 precompute: Aq, Br(+be1), w1r ----------------
__global__ __launch_bounds__(128) void k_pre(const float* __restrict__ qh_new,
                                             const float* __restrict__ rh,
                                             const float* __restrict__ We1,
                                             const float* __restrict__ be1,
                                             float* __restrict__ Aq,
                                             float* __restrict__ Br,
                                             float* __restrict__ w1r) {
    int row = blockIdx.x, o = threadIdx.x;
    __shared__ float xs[D_];
    const float* in; float* out; int off;
    if (row < N_) { in = qh_new + row * D_; out = Aq + row * D_; off = 0; }
    else { in = rh + (row - N_) * D_; out = Br + (row - N_) * D_; off = 128; }
    xs[o] = in[o];
    __syncthreads();
    const float* Wr = We1 + o * 257 + off;
    float acc = 0.f;
#pragma unroll 8
    for (int i = 0; i < 128; i++) acc += Wr[i] * xs[i];
    out[o] = acc + (off ? be1[o] : 0.f);
    if (row == 0) w1r[o] = We1[o * 257 + 256];
}

// ---------------- We2 -> bf16 ----------------
__global__ __launch_bounds__(256) void k_cvt(const float* __restrict__ We2,
                                             unsigned short* __restrict__ We2b) {
    int i = blockIdx.x * 256 + threadIdx.x;
    We2b[i] = f2bf(We2[i]);
}

// ---------------- pair kernel: (n, m-chunk) blocks, 4 waves, MFMA layer-2 ----------------
__global__ __launch_bounds__(256) void k_pair(const float* __restrict__ x_q,
                                              const float* __restrict__ x_r,
                                              const float* __restrict__ Aq,
                                              const float* __restrict__ Br,
                                              const float* __restrict__ w1r,
                                              const float* __restrict__ be2,
                                              const float* __restrict__ Ws,
                                              const unsigned short* __restrict__ We2b,
                                              const float* __restrict__ a_s,
                                              float* __restrict__ dxp) {
    int n = blockIdx.x;
    int chunk = blockIdx.y;
    int cm = chunk * CM_;
    int t = threadIdx.x;
    int w = t >> 6;
    int lane = t & 63;
    int col = lane & 15;   // pair-row within the 16-group / B-p-col
    int kg = lane >> 4;    // k-group

    __shared__ float xr_l[CM_ * 3];
    __shared__ float as_l[CM_];
    __shared__ float Aq_l[D_];
    __shared__ float w1r_l[D_];
    __shared__ float be2_l[D_];
    __shared__ float Ws_l[D_];
    __shared__ float dxw[4][3];

    for (int i = t; i < CM_ * 3; i += 256) xr_l[i] = x_r[cm * 3 + i];
    for (int i = t; i < CM_; i += 256) as_l[i] = a_s[n * M_ + cm + i];
    if (t < D_) {
        Aq_l[t] = Aq[n * D_ + t];
        w1r_l[t] = w1r[t];
        be2_l[t] = be2[t];
        Ws_l[t] = Ws[t];
    }
    __syncthreads();

    // register-resident B fragments: B[o][p] = We2[p][o]
    bf16x8 bf[8][4];
#pragma unroll
    for (int pt = 0; pt < 8; pt++)
#pragma unroll
        for (int kt = 0; kt < 4; kt++)
            bf[pt][kt] = *reinterpret_cast<const bf16x8*>(We2b + (pt * 16 + col) * D_ + kt * 32 + kg * 8);

    float xq0 = x_q[n * 3 + 0], xq1 = x_q[n * 3 + 1], xq2 = x_q[n * 3 + 2];
    float dxa = 0.f, dya = 0.f, dza = 0.f;

#pragma unroll
    for (int it = 0; it < CM_ / 64; it++) {
        int mb = (it * 4 + w) * 16;          // local m-base within chunk
        int pm = mb + col;                   // local pair index
        float d0 = xq0 - xr_l[pm * 3], d1 = xq1 - xr_l[pm * 3 + 1], d2 = xq2 - xr_l[pm * 3 + 2];
        float radial = d0 * d0 + d1 * d1 + d2 * d2;

        bf16x8 af[4];
#pragma unroll
        for (int kt = 0; kt < 4; kt++) {
            int ob = kt * 32 + kg * 8;
            const float4* brp = reinterpret_cast<const float4*>(Br + (cm + pm) * D_ + ob);
            float4 b0 = brp[0], b1 = brp[1];
            float hv[8];
            hv[0] = Aq_l[ob + 0] + b0.x + radial * w1r_l[ob + 0];
            hv[1] = Aq_l[ob + 1] + b0.y + radial * w1r_l[ob + 1];
            hv[2] = Aq_l[ob + 2] + b0.z + radial * w1r_l[ob + 2];
            hv[3] = Aq_l[ob + 3] + b0.w + radial * w1r_l[ob + 3];
            hv[4] = Aq_l[ob + 4] + b1.x + radial * w1r_l[ob + 4];
            hv[5] = Aq_l[ob + 5] + b1.y + radial * w1r_l[ob + 5];
            hv[6] = Aq_l[ob + 6] + b1.z + radial * w1r_l[ob + 6];
            hv[7] = Aq_l[ob + 7] + b1.w + radial * w1r_l[ob + 7];
#pragma unroll
            for (int j = 0; j < 8; j++) af[kt][j] = f2bf_rn(siluf(hv[j]));
        }

        float ssum[4] = {0.f, 0.f, 0.f, 0.f};
#pragma unroll
        for (int pt = 0; pt < 8; pt++) {
            f32x4 acc = {0.f, 0.f, 0.f, 0.f};
#pragma unroll
            for (int kt = 0; kt < 4; kt++)
                acc = __builtin_amdgcn_mfma_f32_16x16x32_bf16(af[kt], bf[pt][kt], acc, 0, 0, 0);
            int p = pt * 16 + col;
            float be = be2_l[p], wsv = Ws_l[p];
#pragma unroll
            for (int r = 0; r < 4; r++) ssum[r] += siluf(acc[r] + be) * wsv;
        }
        // reduce over the 16 cols (p) -> s per pair row kg*4+r
#pragma unroll
        for (int o = 1; o < 16; o <<= 1) {
#pragma unroll
            for (int r = 0; r < 4; r++) ssum[r] += __shfl_xor(ssum[r], o);
        }
        if (col == 0) {
#pragma unroll
            for (int r = 0; r < 4; r++) {
                int m2 = mb + kg * 4 + r;
                float sw = ssum[r] * as_l[m2];
                float e0 = xq0 - xr_l[m2 * 3], e1 = xq1 - xr_l[m2 * 3 + 1], e2 = xq2 - xr_l[m2 * 3 + 2];
                float ir = rsqrtf(e0 * e0 + e1 * e1 + e2 * e2 + 1e-8f);
                dxa += e0 * ir * sw;
                dya += e1 * ir * sw;
                dza += e2 * ir * sw;
            }
        }
    }
    // only lanes 0,16,32,48 hold nonzero partials
    dxa += __shfl_xor(dxa, 16); dxa += __shfl_xor(dxa, 32);
    dya += __shfl_xor(dya, 16); dya += __shfl_xor(dya, 32);
    dza += __shfl_xor(dza, 16); dza += __shfl_xor(dza, 32);
    if (lane == 0) { dxw[w][0] = dxa; dxw[w][1] = dya; dxw[w][2] = dza; }
    __syncthreads();
    if (t == 0) {
        float* o = dxp + (chunk * N_ + n) * 3;
        o[0] = dxw[0][0] + dxw[1][0] + dxw[2][0] + dxw[3][0];
        o[1] = dxw[0][1] + dxw[1][1] + dxw[2][1] + dxw[3][1];
        o[2] = dxw[0][2] + dxw[1][2] + dxw[2][2] + dxw[3][2];
    }
}

// ---------------- finalize x_out = x_q + (sum_ch dxp) * gate ----------------
__global__ __launch_bounds__(256) void k_fin(const float* __restrict__ x_q,
                                             const float* __restrict__ dxp,
                                             const float* __restrict__ gate,
                                             float* __restrict__ x_out) {
    int i = blockIdx.x * 256 + threadIdx.x;
    if (i >= N_ * 3) return;
    int n = i / 3;
    float s = 0.f;
#pragma unroll
    for (int ch = 0; ch < CH_; ch++) s += dxp[(ch * N_ + n) * 3 + (i - n * 3)];
    x_out[i] = x_q[i] + s * gate[n];
}

extern "C" void kernel_launch(void* const* d_in, const int* in_sizes, int n_in,
                              void* d_out, int out_size, void* d_ws, size_t ws_size,
                              hipStream_t stream) {
    const float* h_q   = (const float*)d_in[0];
    const float* x_q   = (const float*)d_in[1];
    const float* h_r   = (const float*)d_in[2];
    const float* x_r   = (const float*)d_in[3];
    // d_in[4], d_in[5]: masks (all true in this problem) -- unused
    const float* Wq    = (const float*)d_in[6];
    const float* bqp   = (const float*)d_in[7];
    const float* Wk    = (const float*)d_in[8];
    const float* bkp   = (const float*)d_in[9];
    const float* Wv    = (const float*)d_in[10];
    const float* bvp   = (const float*)d_in[11];
    const float* Wo    = (const float*)d_in[12];
    const float* bop   = (const float*)d_in[13];
    const float* g_nq  = (const float*)d_in[14];
    const float* b_nq  = (const float*)d_in[15];
    const float* g_nr  = (const float*)d_in[16];
    const float* b_nr  = (const float*)d_in[17];
    const float* g_ff  = (const float*)d_in[18];
    const float* b_ff  = (const float*)d_in[19];
    const float* W1    = (const float*)d_in[20];
    const float* b1    = (const float*)d_in[21];
    const float* W2    = (const float*)d_in[22];
    const float* b2    = (const float*)d_in[23];
    const float* k_null= (const float*)d_in[24];
    const float* v_null= (const float*)d_in[25];
    const float* b_null= (const float*)d_in[26];
    const float* We1   = (const float*)d_in[27];
    const float* be1   = (const float*)d_in[28];
    const float* We2   = (const float*)d_in[29];
    const float* be2   = (const float*)d_in[30];
    const float* Ws    = (const float*)d_in[31];

    float* ws     = (float*)d_ws;
    float* qh     = ws;                  // N*D
    float* rh     = qh + N_ * D_;        // M*D
    float* q      = rh + M_ * D_;        // N*D
    float* k      = q + N_ * D_;         // M*D
    float* v      = k + M_ * D_;         // M*D
    float* a_s    = v + M_ * D_;         // N*M
    float* gate   = a_s + N_ * M_;       // N
    float* msg    = gate + N_;           // N*D
    float* h_mid  = msg + N_ * D_;       // N*D
    float* t_ln   = h_mid + N_ * D_;     // N*D
    float* ffh    = t_ln + N_ * D_;      // N*FF
    float* qh_new = ffh + N_ * FF_;      // N*D
    float* Aq     = qh_new + N_ * D_;    // N*D
    float* Br     = Aq + N_ * D_;        // M*D
    float* w1r    = Br + M_ * D_;        // D
    unsigned short* We2b = (unsigned short*)(w1r + D_);  // D*D bf16
    float* dxp    = (float*)(We2b + D_ * D_);            // CH*N*3

    float* h_out = (float*)d_out;        // N*D
    float* x_out = h_out + N_ * D_;      // N*3

    k_ln<<<N_, 64, 0, stream>>>(h_q, g_nq, b_nq, qh);
    k_ln<<<M_, 64, 0, stream>>>(h_r, g_nr, b_nr, rh);
    k_cvt<<<64, 256, 0, stream>>>(We2, We2b);
    k_qkv<<<dim3(N_, 3), 128, 0, stream>>>(qh, rh, h_r, Wq, bqp, Wk, bkp, Wv, bvp, q, k, v);
    k_attn<<<N_, 256, 0, stream>>>(q, k, v, k_null, v_null, b_null, a_s, gate, msg);
    k_outproj<<<N_, 128, 0, stream>>>(h_q, msg, Wo, bop, h_mid);
    k_ln<<<N_, 64, 0, stream>>>(h_mid, g_ff, b_ff, t_ln);
    k_ffn1<<<N_, 256, 0, stream>>>(t_ln, W1, b1, ffh);
    k_ffn2<<<N_, 128, 0, stream>>>(h_mid, ffh, W2, b2, h_out);
    k_ln<<<N_, 64, 0, stream>>>(h_out, g_nq, b_nq, qh_new);
    k_pre<<<N_ + M_, 128, 0, stream>>>(qh_new, rh, We1, be1, Aq, Br, w1r);
    k_pair<<<dim3(N_, CH_), 256, 0, stream>>>(x_q, x_r, Aq, Br, w1r, be2, Ws, We2b, a_s, dxp);
    k_fin<<<9, 256, 0, stream>>>(x_q, dxp, gate, x_out);
}

// Round 3
// 282.689 us; speedup vs baseline: 1.2828x; 1.0427x over previous
//
#include <hip/hip_runtime.h>
#include <hip/hip_bf16.h>
#include <math.h>

#define N_ 768
#define M_ 768
#define D_ 128
#define H_ 8
#define DH_ 16
#define FF_ 512
#define CH_ 6
#define CM_ 128   // M_/CH_

typedef float f32x4 __attribute__((ext_vector_type(4)));
typedef short bf16x8 __attribute__((ext_vector_type(8)));

__device__ __forceinline__ float siluf(float x) {
    // x * sigmoid(x) with raw v_rcp (2^-22 rel err, way below bf16 rounding)
    return x * __builtin_amdgcn_rcpf(1.0f + __expf(-x));
}

__device__ __forceinline__ unsigned short f2bf(float x) {
    unsigned int u = __float_as_uint(x);
    unsigned int r = (u + 0x7fffu + ((u >> 16) & 1u)) >> 16;
    return (unsigned short)r;
}

__device__ __forceinline__ short f2bf_rn(float x) {
    __hip_bfloat16 b = __float2bfloat16(x);
    return (short)*reinterpret_cast<unsigned short*>(&b);
}

// ---- LN for qh & rh rows + We2->bf16 cvt + We1 transpose (folded prep) ----
__global__ __launch_bounds__(64) void k_ln2(const float* __restrict__ h_q,
                                            const float* __restrict__ h_r,
                                            const float* __restrict__ g_nq, const float* __restrict__ b_nq,
                                            const float* __restrict__ g_nr, const float* __restrict__ b_nr,
                                            float* __restrict__ qh, float* __restrict__ rh,
                                            const float* __restrict__ We2, unsigned short* __restrict__ We2b,
                                            const float* __restrict__ We1, float* __restrict__ We1a) {
    int row = blockIdx.x, lane = threadIdx.x;
    const float *src, *g, *b; float* dst;
    if (row < N_) { src = h_q + row * D_; g = g_nq; b = b_nq; dst = qh + row * D_; }
    else { src = h_r + (row - N_) * D_; g = g_nr; b = b_nr; dst = rh + (row - N_) * D_; }
    float x0 = src[lane], x1 = src[lane + 64];
    float s = x0 + x1;
#pragma unroll
    for (int o = 32; o > 0; o >>= 1) s += __shfl_xor(s, o);
    float mu = s * (1.f / 128.f);
    float d0 = x0 - mu, d1 = x1 - mu;
    float v2 = d0 * d0 + d1 * d1;
#pragma unroll
    for (int o = 32; o > 0; o >>= 1) v2 += __shfl_xor(v2, o);
    float inv = rsqrtf(v2 * (1.f / 128.f) + 1e-5f);
    dst[lane] = d0 * inv * g[lane] + b[lane];
    dst[lane + 64] = d1 * inv * g[lane + 64] + b[lane + 64];
    // prep work piggybacked on early blocks
    if (row < D_) {
        We2b[row * D_ + lane] = f2bf(We2[row * D_ + lane]);
        We2b[row * D_ + lane + 64] = f2bf(We2[row * D_ + lane + 64]);
    }
    if (row <= 256) {  // We1a[c][j] = We1[j][c], c=row (257 rows incl radial col -> w1r)
        We1a[row * D_ + lane] = We1[lane * 257 + row];
        We1a[row * D_ + lane + 64] = We1[(lane + 64) * 257 + row];
    }
}

// ---- q/k/v projections, 8 rows per block ----
__global__ __launch_bounds__(128) void k_qkv(const float* __restrict__ qh,
                                             const float* __restrict__ rh,
                                             const float* __restrict__ h_r,
                                             const float* __restrict__ Wq, const float* __restrict__ bq,
                                             const float* __restrict__ Wk, const float* __restrict__ bk,
                                             const float* __restrict__ Wv, const float* __restrict__ bv,
                                             float* __restrict__ q, float* __restrict__ k, float* __restrict__ v) {
    int r0 = blockIdx.x * 8, which = blockIdx.y, j = threadIdx.x;
    const float* in; const float* W; const float* b; float* out;
    if (which == 0) { in = qh; W = Wq; b = bq; out = q; }
    else if (which == 1) { in = rh; W = Wk; b = bk; out = k; }
    else { in = h_r; W = Wv; b = bv; out = v; }
    __shared__ float xs[8][D_];
    for (int i = j; i < 8 * D_; i += 128) xs[i >> 7][i & 127] = in[r0 * D_ + i];
    __syncthreads();
    const float4* Wr = (const float4*)(W + j * D_);
    float acc[8] = {0, 0, 0, 0, 0, 0, 0, 0};
    for (int i = 0; i < 32; i++) {
        float4 w = Wr[i];
#pragma unroll
        for (int r = 0; r < 8; r++) {
            float4 x = ((const float4*)xs[r])[i];
            acc[r] += w.x * x.x + w.y * x.y + w.z * x.z + w.w * x.w;
        }
    }
    float bb = b[j];
#pragma unroll
    for (int r = 0; r < 8; r++) out[(r0 + r) * D_ + j] = acc[r] + bb;
}

// ---- attention: one block per n, loop heads ----
__global__ __launch_bounds__(256) void k_attn(const float* __restrict__ q,
                                              const float* __restrict__ k,
                                              const float* __restrict__ v,
                                              const float* __restrict__ k_null,
                                              const float* __restrict__ v_null,
                                              const float* __restrict__ b_null,
                                              float* __restrict__ a_s,
                                              float* __restrict__ gate,
                                              float* __restrict__ msg) {
    int n = blockIdx.x, t = threadIdx.x;
    int lane = t & 63, wid = t >> 6;
    __shared__ float sc[M_];
    __shared__ float as_l[M_];
    __shared__ float redm[4], reds[4];
    __shared__ float part[256];
#pragma unroll
    for (int c = 0; c < 3; c++) as_l[t + 256 * c] = 0.f;
    float gate_acc = 0.f;
    const float inv = 0.25f;

    for (int h = 0; h < H_; h++) {
        float qr[DH_];
        const float* qp = q + n * D_ + h * DH_;
#pragma unroll
        for (int d = 0; d < DH_; d++) qr[d] = qp[d];
        float ll[3]; float lmax = -3.4e38f;
#pragma unroll
        for (int c = 0; c < 3; c++) {
            int m = t + 256 * c;
            const float* kp = k + m * D_ + h * DH_;
            float acc = 0.f;
#pragma unroll
            for (int d = 0; d < DH_; d++) acc += qr[d] * kp[d];
            acc *= inv;
            ll[c] = acc;
            lmax = fmaxf(lmax, acc);
        }
        __syncthreads();
#pragma unroll
        for (int o = 32; o > 0; o >>= 1) lmax = fmaxf(lmax, __shfl_xor(lmax, o));
        if (lane == 0) redm[wid] = lmax;
        __syncthreads();
        float mx = fmaxf(fmaxf(redm[0], redm[1]), fmaxf(redm[2], redm[3]));
        float es = 0.f;
#pragma unroll
        for (int c = 0; c < 3; c++) es += __expf(ll[c] - mx);
#pragma unroll
        for (int o = 32; o > 0; o >>= 1) es += __shfl_xor(es, o);
        if (lane == 0) reds[wid] = es;
        __syncthreads();
        float sum = reds[0] + reds[1] + reds[2] + reds[3];

        float lnull;
        {
            const float* kp = k_null + h * DH_;
            float acc = 0.f;
#pragma unroll
            for (int d = 0; d < DH_; d++) acc += qr[d] * kp[d];
            lnull = acc * inv + b_null[h];
        }
        float lse_real = mx + __logf(sum + 1e-9f);
        float m2 = fmaxf(lse_real, lnull);
        float lse_all = m2 + __logf(__expf(lse_real - m2) + __expf(lnull - m2));
        float a_null = __expf(lnull - lse_all);
        gate_acc += fminf(1.f, __expf(lse_real - lse_all));
#pragma unroll
        for (int c = 0; c < 3; c++) {
            int m = t + 256 * c;
            float a = __expf(ll[c] - lse_all);
            sc[m] = a;
            as_l[m] += 0.125f * a;
        }
        __syncthreads();
        int d = t & 15, gI = t >> 4;
        float p = 0.f;
        int mbase = gI * 48;
        for (int i = 0; i < 48; i++) {
            int m = mbase + i;
            p += sc[m] * v[m * D_ + h * DH_ + d];
        }
        part[t] = p;
        __syncthreads();
        if (t < DH_) {
            float s3 = 0.f;
#pragma unroll
            for (int g2 = 0; g2 < 16; g2++) s3 += part[g2 * 16 + t];
            msg[n * D_ + h * DH_ + t] = s3 + a_null * v_null[h * DH_ + t];
        }
    }
    __syncthreads();
#pragma unroll
    for (int c = 0; c < 3; c++) a_s[n * M_ + t + 256 * c] = as_l[t + 256 * c];
    if (t == 0) gate[n] = gate_acc * 0.125f;
}

// ---- fused outproj + LN + ffn1 + ffn2 + LN, 8 rows per block ----
__global__ __launch_bounds__(256) void k_mlp(const float* __restrict__ h_q,
                                             const float* __restrict__ msg,
                                             const float* __restrict__ Wo, const float* __restrict__ bop,
                                             const float* __restrict__ g_ff, const float* __restrict__ b_ff,
                                             const float* __restrict__ W1, const float* __restrict__ b1,
                                             const float* __restrict__ W2, const float* __restrict__ b2,
                                             const float* __restrict__ g_nq, const float* __restrict__ b_nq,
                                             float* __restrict__ h_out, float* __restrict__ qh_new) {
    int r0 = blockIdx.x * 8;
    int t = threadIdx.x;
    __shared__ float xs[8][D_];
    __shared__ float hm[8][D_];
    __shared__ float tl[8][D_];
    __shared__ float ffh[8][FF_];
    for (int i = t; i < 8 * D_; i += 256) xs[i >> 7][i & 127] = msg[r0 * D_ + i];
    __syncthreads();
    // P1: outproj + residual -> hm
    {
        int g = t >> 7, j = t & 127;
        float acc[4] = {0, 0, 0, 0};
        const float4* Wr = (const float4*)(Wo + j * D_);
        for (int i = 0; i < 32; i++) {
            float4 w = Wr[i];
#pragma unroll
            for (int r = 0; r < 4; r++) {
                float4 x = ((const float4*)xs[4 * g + r])[i];
                acc[r] += w.x * x.x + w.y * x.y + w.z * x.z + w.w * x.w;
            }
        }
        float bb = bop[j];
#pragma unroll
        for (int r = 0; r < 4; r++)
            hm[4 * g + r][j] = h_q[(r0 + 4 * g + r) * D_ + j] + acc[r] + bb;
    }
    __syncthreads();
    // P2: LN(hm) -> tl
    {
        int r = t >> 5, l = t & 31;
        float v0 = hm[r][l], v1 = hm[r][l + 32], v2 = hm[r][l + 64], v3 = hm[r][l + 96];
        float s = v0 + v1 + v2 + v3;
#pragma unroll
        for (int o = 1; o < 32; o <<= 1) s += __shfl_xor(s, o);
        float mu = s * (1.f / 128.f);
        float d0 = v0 - mu, d1 = v1 - mu, d2 = v2 - mu, d3 = v3 - mu;
        float vv = d0 * d0 + d1 * d1 + d2 * d2 + d3 * d3;
#pragma unroll
        for (int o = 1; o < 32; o <<= 1) vv += __shfl_xor(vv, o);
        float inv = rsqrtf(vv * (1.f / 128.f) + 1e-5f);
        tl[r][l] = d0 * inv * g_ff[l] + b_ff[l];
        tl[r][l + 32] = d1 * inv * g_ff[l + 32] + b_ff[l + 32];
        tl[r][l + 64] = d2 * inv * g_ff[l + 64] + b_ff[l + 64];
        tl[r][l + 96] = d3 * inv * g_ff[l + 96] + b_ff[l + 96];
    }
    __syncthreads();
    // P3: ffn1 + silu -> ffh (2 outputs per thread)
    {
        int j0 = t, j1 = t + 256;
        float a0[8] = {0}, a1[8] = {0};
        const float4* Wa = (const float4*)(W1 + j0 * D_);
        const float4* Wb = (const float4*)(W1 + j1 * D_);
        for (int i = 0; i < 32; i++) {
            float4 wa = Wa[i], wb = Wb[i];
#pragma unroll
            for (int r = 0; r < 8; r++) {
                float4 x = ((const float4*)tl[r])[i];
                a0[r] += wa.x * x.x + wa.y * x.y + wa.z * x.z + wa.w * x.w;
                a1[r] += wb.x * x.x + wb.y * x.y + wb.z * x.z + wb.w * x.w;
            }
        }
        float bb0 = b1[j0], bb1 = b1[j1];
#pragma unroll
        for (int r = 0; r < 8; r++) {
            ffh[r][j0] = siluf(a0[r] + bb0);
            ffh[r][j1] = siluf(a1[r] + bb1);
        }
    }
    __syncthreads();
    // P4: ffn2 + residual -> h_out global, hm reused as ho
    {
        int g = t >> 7, j = t & 127;
        float acc[4] = {0, 0, 0, 0};
        const float4* Wr = (const float4*)(W2 + j * FF_);
        for (int i = 0; i < 128; i++) {
            float4 w = Wr[i];
#pragma unroll
            for (int r = 0; r < 4; r++) {
                float4 x = ((const float4*)ffh[4 * g + r])[i];
                acc[r] += w.x * x.x + w.y * x.y + w.z * x.z + w.w * x.w;
            }
        }
        float bb = b2[j];
#pragma unroll
        for (int r = 0; r < 4; r++) {
            float vv = hm[4 * g + r][j] + acc[r] + bb;
            h_out[(r0 + 4 * g + r) * D_ + j] = vv;
            hm[4 * g + r][j] = vv;
        }
    }
    __syncthreads();
    // P5: LN(h_out rows) -> qh_new
    {
        int r = t >> 5, l = t & 31;
        float v0 = hm[r][l], v1 = hm[r][l + 32], v2 = hm[r][l + 64], v3 = hm[r][l + 96];
        float s = v0 + v1 + v2 + v3;
#pragma unroll
        for (int o = 1; o < 32; o <<= 1) s += __shfl_xor(s, o);
        float mu = s * (1.f / 128.f);
        float d0 = v0 - mu, d1 = v1 - mu, d2 = v2 - mu, d3 = v3 - mu;
        float vv = d0 * d0 + d1 * d1 + d2 * d2 + d3 * d3;
#pragma unroll
        for (int o = 1; o < 32; o <<= 1) vv += __shfl_xor(vv, o);
        float inv = rsqrtf(vv * (1.f / 128.f) + 1e-5f);
        int rr = (r0 + r) * D_;
        qh_new[rr + l] = d0 * inv * g_nq[l] + b_nq[l];
        qh_new[rr + l + 32] = d1 * inv * g_nq[l + 32] + b_nq[l + 32];
        qh_new[rr + l + 64] = d2 * inv * g_nq[l + 64] + b_nq[l + 64];
        qh_new[rr + l + 96] = d3 * inv * g_nq[l + 96] + b_nq[l + 96];
    }
}

// ---- edge-MLP layer-1 precompute from transposed We1a, 16 rows per block ----
__global__ __launch_bounds__(256) void k_pre(const float* __restrict__ qh_new,
                                             const float* __restrict__ rh,
                                             const float* __restrict__ We1a,
                                             const float* __restrict__ be1,
                                             float* __restrict__ Aq,
                                             float* __restrict__ Br) {
    int bb = blockIdx.x;               // 0..95
    int half = bb >= 48;
    int r0 = (bb - half * 48) * 16;
    int off = half * 128;
    int t = threadIdx.x;
    int r = t >> 4, jg = t & 15;       // row 0..15, j-group of 8
    __shared__ float xs[16][D_];
    const float* in = (half ? rh : qh_new) + r0 * D_;
    for (int i = t; i < 16 * D_; i += 256) xs[i >> 7][i & 127] = in[i];
    __syncthreads();
    float acc[8] = {0};
    const float* xr = xs[r];
    for (int i = 0; i < 128; i++) {
        float x = xr[i];
        const float4 w0 = *(const float4*)(We1a + (off + i) * D_ + jg * 8);
        const float4 w1 = *(const float4*)(We1a + (off + i) * D_ + jg * 8 + 4);
        acc[0] += w0.x * x; acc[1] += w0.y * x; acc[2] += w0.z * x; acc[3] += w0.w * x;
        acc[4] += w1.x * x; acc[5] += w1.y * x; acc[6] += w1.z * x; acc[7] += w1.w * x;
    }
    float* out = (half ? Br : Aq) + (r0 + r) * D_ + jg * 8;
    if (half) {
        const float4 e0 = *(const float4*)(be1 + jg * 8);
        const float4 e1 = *(const float4*)(be1 + jg * 8 + 4);
        acc[0] += e0.x; acc[1] += e0.y; acc[2] += e0.z; acc[3] += e0.w;
        acc[4] += e1.x; acc[5] += e1.y; acc[6] += e1.z; acc[7] += e1.w;
    }
    *(float4*)(out) = make_float4(acc[0], acc[1], acc[2], acc[3]);
    *(float4*)(out + 4) = make_float4(acc[4], acc[5], acc[6], acc[7]);
}

// ---- pair kernel: (n, m-chunk) blocks, 4 waves, MFMA layer-2 ----
__global__ __launch_bounds__(256, 4) void k_pair(const float* __restrict__ x_q,
                                                 const float* __restrict__ x_r,
                                                 const float* __restrict__ Aq,
                                                 const float* __restrict__ Br,
                                                 const float* __restrict__ w1r,
                                                 const float* __restrict__ be2,
                                                 const float* __restrict__ Ws,
                                                 const unsigned short* __restrict__ We2b,
                                                 const float* __restrict__ a_s,
                                                 float* __restrict__ dxp) {
    int n = blockIdx.x;
    int chunk = blockIdx.y;
    int cm = chunk * CM_;
    int t = threadIdx.x;
    int w = t >> 6;
    int lane = t & 63;
    int col = lane & 15;
    int kg = lane >> 4;

    __shared__ float xr_l[CM_ * 3];
    __shared__ float as_l[CM_];
    __shared__ float Aq_l[D_];
    __shared__ float w1r_l[D_];
    __shared__ float2 bw_l[D_];
    __shared__ float dxw[4][3];

    for (int i = t; i < CM_ * 3; i += 256) xr_l[i] = x_r[cm * 3 + i];
    if (t < CM_) as_l[t] = a_s[n * M_ + cm + t];
    if (t < D_) {
        Aq_l[t] = Aq[n * D_ + t];
        w1r_l[t] = w1r[t];
        bw_l[t] = make_float2(be2[t], Ws[t]);
    }
    __syncthreads();

    // register-resident B fragments: B[o][p] = We2[p][o]
    bf16x8 bf[8][4];
#pragma unroll
    for (int pt = 0; pt < 8; pt++)
#pragma unroll
        for (int kt = 0; kt < 4; kt++)
            bf[pt][kt] = *reinterpret_cast<const bf16x8*>(We2b + (pt * 16 + col) * D_ + kt * 32 + kg * 8);

    float xq0 = x_q[n * 3 + 0], xq1 = x_q[n * 3 + 1], xq2 = x_q[n * 3 + 2];
    float dxa = 0.f, dya = 0.f, dza = 0.f;

#pragma unroll
    for (int it = 0; it < CM_ / 64; it++) {
        int mb = (it * 4 + w) * 16;
        int pm = mb + col;
        float d0 = xq0 - xr_l[pm * 3], d1 = xq1 - xr_l[pm * 3 + 1], d2 = xq2 - xr_l[pm * 3 + 2];
        float radial = d0 * d0 + d1 * d1 + d2 * d2;

        bf16x8 af[4];
#pragma unroll
        for (int kt = 0; kt < 4; kt++) {
            int ob = kt * 32 + kg * 8;
            const float4* brp = reinterpret_cast<const float4*>(Br + (cm + pm) * D_ + ob);
            float4 b0 = brp[0], b1 = brp[1];
            const float4 a0 = *(const float4*)(Aq_l + ob), a1 = *(const float4*)(Aq_l + ob + 4);
            const float4 w0 = *(const float4*)(w1r_l + ob), w1 = *(const float4*)(w1r_l + ob + 4);
            float hv[8];
            hv[0] = a0.x + b0.x + radial * w0.x;
            hv[1] = a0.y + b0.y + radial * w0.y;
            hv[2] = a0.z + b0.z + radial * w0.z;
            hv[3] = a0.w + b0.w + radial * w0.w;
            hv[4] = a1.x + b1.x + radial * w1.x;
            hv[5] = a1.y + b1.y + radial * w1.y;
            hv[6] = a1.z + b1.z + radial * w1.z;
            hv[7] = a1.w + b1.w + radial * w1.w;
#pragma unroll
            for (int j = 0; j < 8; j++) af[kt][j] = f2bf_rn(siluf(hv[j]));
        }

        float ssum[4] = {0.f, 0.f, 0.f, 0.f};
#pragma unroll
        for (int pt = 0; pt < 8; pt++) {
            f32x4 acc = {0.f, 0.f, 0.f, 0.f};
#pragma unroll
            for (int kt = 0; kt < 4; kt++)
                acc = __builtin_amdgcn_mfma_f32_16x16x32_bf16(af[kt], bf[pt][kt], acc, 0, 0, 0);
            int p = pt * 16 + col;
            float2 bw = bw_l[p];
#pragma unroll
            for (int r = 0; r < 4; r++) ssum[r] += siluf(acc[r] + bw.x) * bw.y;
        }
#pragma unroll
        for (int o = 1; o < 16; o <<= 1) {
#pragma unroll
            for (int r = 0; r < 4; r++) ssum[r] += __shfl_xor(ssum[r], o);
        }
        if (col == 0) {
#pragma unroll
            for (int r = 0; r < 4; r++) {
                int m2 = mb + kg * 4 + r;
                float sw = ssum[r] * as_l[m2];
                float e0 = xq0 - xr_l[m2 * 3], e1 = xq1 - xr_l[m2 * 3 + 1], e2 = xq2 - xr_l[m2 * 3 + 2];
                float ir = rsqrtf(e0 * e0 + e1 * e1 + e2 * e2 + 1e-8f);
                dxa += e0 * ir * sw;
                dya += e1 * ir * sw;
                dza += e2 * ir * sw;
            }
        }
    }
    dxa += __shfl_xor(dxa, 16); dxa += __shfl_xor(dxa, 32);
    dya += __shfl_xor(dya, 16); dya += __shfl_xor(dya, 32);
    dza += __shfl_xor(dza, 16); dza += __shfl_xor(dza, 32);
    if (lane == 0) { dxw[w][0] = dxa; dxw[w][1] = dya; dxw[w][2] = dza; }
    __syncthreads();
    if (t == 0) {
        float* o = dxp + (chunk * N_ + n) * 3;
        o[0] = dxw[0][0] + dxw[1][0] + dxw[2][0] + dxw[3][0];
        o[1] = dxw[0][1] + dxw[1][1] + dxw[2][1] + dxw[3][1];
        o[2] = dxw[0][2] + dxw[1][2] + dxw[2][2] + dxw[3][2];
    }
}

// ---- finalize ----
__global__ __launch_bounds__(256) void k_fin(const float* __restrict__ x_q,
                                             const float* __restrict__ dxp,
                                             const float* __restrict__ gate,
                                             float* __restrict__ x_out) {
    int i = blockIdx.x * 256 + threadIdx.x;
    if (i >= N_ * 3) return;
    int n = i / 3;
    float s = 0.f;
#pragma unroll
    for (int ch = 0; ch < CH_; ch++) s += dxp[(ch * N_ + n) * 3 + (i - n * 3)];
    x_out[i] = x_q[i] + s * gate[n];
}

extern "C" void kernel_launch(void* const* d_in, const int* in_sizes, int n_in,
                              void* d_out, int out_size, void* d_ws, size_t ws_size,
                              hipStream_t stream) {
    const float* h_q   = (const float*)d_in[0];
    const float* x_q   = (const float*)d_in[1];
    const float* h_r   = (const float*)d_in[2];
    const float* x_r   = (const float*)d_in[3];
    const float* Wq    = (const float*)d_in[6];
    const float* bqp   = (const float*)d_in[7];
    const float* Wk    = (const float*)d_in[8];
    const float* bkp   = (const float*)d_in[9];
    const float* Wv    = (const float*)d_in[10];
    const float* bvp   = (const float*)d_in[11];
    const float* Wo    = (const float*)d_in[12];
    const float* bop   = (const float*)d_in[13];
    const float* g_nq  = (const float*)d_in[14];
    const float* b_nq  = (const float*)d_in[15];
    const float* g_nr  = (const float*)d_in[16];
    const float* b_nr  = (const float*)d_in[17];
    const float* g_ff  = (const float*)d_in[18];
    const float* b_ff  = (const float*)d_in[19];
    const float* W1    = (const float*)d_in[20];
    const float* b1    = (const float*)d_in[21];
    const float* W2    = (const float*)d_in[22];
    const float* b2    = (const float*)d_in[23];
    const float* k_null= (const float*)d_in[24];
    const float* v_null= (const float*)d_in[25];
    const float* b_null= (const float*)d_in[26];
    const float* We1   = (const float*)d_in[27];
    const float* be1   = (const float*)d_in[28];
    const float* We2   = (const float*)d_in[29];
    const float* be2   = (const float*)d_in[30];
    const float* Ws    = (const float*)d_in[31];

    float* ws     = (float*)d_ws;
    float* qh     = ws;                   // N*D
    float* rh     = qh + N_ * D_;         // M*D
    float* q      = rh + M_ * D_;         // N*D
    float* k      = q + N_ * D_;          // M*D
    float* v      = k + M_ * D_;          // M*D
    float* a_s    = v + M_ * D_;          // N*M
    float* gate   = a_s + N_ * M_;        // N
    float* msg    = gate + N_;            // N*D
    float* qh_new = msg + N_ * D_;        // N*D
    float* Aq     = qh_new + N_ * D_;     // N*D
    float* Br     = Aq + N_ * D_;         // M*D
    float* We1a   = Br + M_ * D_;         // 257*128 (row 256 = w1r)
    float* dxp    = We1a + 257 * D_;      // CH*N*3
    unsigned short* We2b = (unsigned short*)(dxp + CH_ * N_ * 3);  // D*D bf16
    float* w1r    = We1a + 256 * D_;

    float* h_out = (float*)d_out;         // N*D
    float* x_out = h_out + N_ * D_;       // N*3

    k_ln2<<<N_ + M_, 64, 0, stream>>>(h_q, h_r, g_nq, b_nq, g_nr, b_nr, qh, rh, We2, We2b, We1, We1a);
    k_qkv<<<dim3(96, 3), 128, 0, stream>>>(qh, rh, h_r, Wq, bqp, Wk, bkp, Wv, bvp, q, k, v);
    k_attn<<<N_, 256, 0, stream>>>(q, k, v, k_null, v_null, b_null, a_s, gate, msg);
    k_mlp<<<96, 256, 0, stream>>>(h_q, msg, Wo, bop, g_ff, b_ff, W1, b1, W2, b2, g_nq, b_nq, h_out, qh_new);
    k_pre<<<96, 256, 0, stream>>>(qh_new, rh, We1a, be1, Aq, Br);
    k_pair<<<dim3(N_, CH_), 256, 0, stream>>>(x_q, x_r, Aq, Br, w1r, be2, Ws, We2b, a_s, dxp);
    k_fin<<<9, 256, 0, stream>>>(x_q, dxp, gate, x_out);
}

// Round 4
// 201.054 us; speedup vs baseline: 1.8037x; 1.4060x over previous
//
#include <hip/hip_runtime.h>
#include <hip/hip_bf16.h>
#include <math.h>

#define N_ 768
#define M_ 768
#define D_ 128
#define H_ 8
#define DH_ 16
#define FF_ 512
#define CH_ 4
#define CM_ 192   // M_/CH_

typedef float f32x4 __attribute__((ext_vector_type(4)));
typedef short bf16x8 __attribute__((ext_vector_type(8)));

__device__ __forceinline__ float siluf(float x) {
    // x * sigmoid(x) with raw v_rcp (2^-22 rel err, way below bf16 rounding)
    return x * __builtin_amdgcn_rcpf(1.0f + __expf(-x));
}

__device__ __forceinline__ unsigned short f2bf(float x) {
    unsigned int u = __float_as_uint(x);
    unsigned int r = (u + 0x7fffu + ((u >> 16) & 1u)) >> 16;
    return (unsigned short)r;
}

__device__ __forceinline__ short f2bf_rn(float x) {
    __hip_bfloat16 b = __float2bfloat16(x);
    return (short)*reinterpret_cast<unsigned short*>(&b);
}

// ---- LN for qh & rh rows + We2->bf16 cvt + We1 transpose (folded prep) ----
__global__ __launch_bounds__(64) void k_ln2(const float* __restrict__ h_q,
                                            const float* __restrict__ h_r,
                                            const float* __restrict__ g_nq, const float* __restrict__ b_nq,
                                            const float* __restrict__ g_nr, const float* __restrict__ b_nr,
                                            float* __restrict__ qh, float* __restrict__ rh,
                                            const float* __restrict__ We2, unsigned short* __restrict__ We2b,
                                            const float* __restrict__ We1, float* __restrict__ We1a) {
    int row = blockIdx.x, lane = threadIdx.x;
    const float *src, *g, *b; float* dst;
    if (row < N_) { src = h_q + row * D_; g = g_nq; b = b_nq; dst = qh + row * D_; }
    else { src = h_r + (row - N_) * D_; g = g_nr; b = b_nr; dst = rh + (row - N_) * D_; }
    float x0 = src[lane], x1 = src[lane + 64];
    float s = x0 + x1;
#pragma unroll
    for (int o = 32; o > 0; o >>= 1) s += __shfl_xor(s, o);
    float mu = s * (1.f / 128.f);
    float d0 = x0 - mu, d1 = x1 - mu;
    float v2 = d0 * d0 + d1 * d1;
#pragma unroll
    for (int o = 32; o > 0; o >>= 1) v2 += __shfl_xor(v2, o);
    float inv = rsqrtf(v2 * (1.f / 128.f) + 1e-5f);
    dst[lane] = d0 * inv * g[lane] + b[lane];
    dst[lane + 64] = d1 * inv * g[lane + 64] + b[lane + 64];
    // prep work piggybacked on early blocks
    if (row < D_) {
        We2b[row * D_ + lane] = f2bf(We2[row * D_ + lane]);
        We2b[row * D_ + lane + 64] = f2bf(We2[row * D_ + lane + 64]);
    }
    if (row <= 256) {  // We1a[c][j] = We1[j][c], c=row (257 rows incl radial col -> w1r)
        We1a[row * D_ + lane] = We1[lane * 257 + row];
        We1a[row * D_ + lane + 64] = We1[(lane + 64) * 257 + row];
    }
}

// ---- q/k/v projections, 8 rows per block ----
__global__ __launch_bounds__(128) void k_qkv(const float* __restrict__ qh,
                                             const float* __restrict__ rh,
                                             const float* __restrict__ h_r,
                                             const float* __restrict__ Wq, const float* __restrict__ bq,
                                             const float* __restrict__ Wk, const float* __restrict__ bk,
                                             const float* __restrict__ Wv, const float* __restrict__ bv,
                                             float* __restrict__ q, float* __restrict__ k, float* __restrict__ v) {
    int r0 = blockIdx.x * 8, which = blockIdx.y, j = threadIdx.x;
    const float* in; const float* W; const float* b; float* out;
    if (which == 0) { in = qh; W = Wq; b = bq; out = q; }
    else if (which == 1) { in = rh; W = Wk; b = bk; out = k; }
    else { in = h_r; W = Wv; b = bv; out = v; }
    __shared__ float xs[8][D_];
    for (int i = j; i < 8 * D_; i += 128) xs[i >> 7][i & 127] = in[r0 * D_ + i];
    __syncthreads();
    const float4* Wr = (const float4*)(W + j * D_);
    float acc[8] = {0, 0, 0, 0, 0, 0, 0, 0};
    for (int i = 0; i < 32; i++) {
        float4 w = Wr[i];
#pragma unroll
        for (int r = 0; r < 8; r++) {
            float4 x = ((const float4*)xs[r])[i];
            acc[r] += w.x * x.x + w.y * x.y + w.z * x.z + w.w * x.w;
        }
    }
    float bb = b[j];
#pragma unroll
    for (int r = 0; r < 8; r++) out[(r0 + r) * D_ + j] = acc[r] + bb;
}

// ---- attention: one block per n, loop heads ----
__global__ __launch_bounds__(256) void k_attn(const float* __restrict__ q,
                                              const float* __restrict__ k,
                                              const float* __restrict__ v,
                                              const float* __restrict__ k_null,
                                              const float* __restrict__ v_null,
                                              const float* __restrict__ b_null,
                                              float* __restrict__ a_s,
                                              float* __restrict__ gate,
                                              float* __restrict__ msg) {
    int n = blockIdx.x, t = threadIdx.x;
    int lane = t & 63, wid = t >> 6;
    __shared__ float sc[M_];
    __shared__ float as_l[M_];
    __shared__ float redm[4], reds[4];
    __shared__ float part[256];
#pragma unroll
    for (int c = 0; c < 3; c++) as_l[t + 256 * c] = 0.f;
    float gate_acc = 0.f;
    const float inv = 0.25f;

    for (int h = 0; h < H_; h++) {
        float qr[DH_];
        const float* qp = q + n * D_ + h * DH_;
#pragma unroll
        for (int d = 0; d < DH_; d++) qr[d] = qp[d];
        float ll[3]; float lmax = -3.4e38f;
#pragma unroll
        for (int c = 0; c < 3; c++) {
            int m = t + 256 * c;
            const float* kp = k + m * D_ + h * DH_;
            float acc = 0.f;
#pragma unroll
            for (int d = 0; d < DH_; d++) acc += qr[d] * kp[d];
            acc *= inv;
            ll[c] = acc;
            lmax = fmaxf(lmax, acc);
        }
        __syncthreads();
#pragma unroll
        for (int o = 32; o > 0; o >>= 1) lmax = fmaxf(lmax, __shfl_xor(lmax, o));
        if (lane == 0) redm[wid] = lmax;
        __syncthreads();
        float mx = fmaxf(fmaxf(redm[0], redm[1]), fmaxf(redm[2], redm[3]));
        float es = 0.f;
#pragma unroll
        for (int c = 0; c < 3; c++) es += __expf(ll[c] - mx);
#pragma unroll
        for (int o = 32; o > 0; o >>= 1) es += __shfl_xor(es, o);
        if (lane == 0) reds[wid] = es;
        __syncthreads();
        float sum = reds[0] + reds[1] + reds[2] + reds[3];

        float lnull;
        {
            const float* kp = k_null + h * DH_;
            float acc = 0.f;
#pragma unroll
            for (int d = 0; d < DH_; d++) acc += qr[d] * kp[d];
            lnull = acc * inv + b_null[h];
        }
        float lse_real = mx + __logf(sum + 1e-9f);
        float m2 = fmaxf(lse_real, lnull);
        float lse_all = m2 + __logf(__expf(lse_real - m2) + __expf(lnull - m2));
        float a_null = __expf(lnull - lse_all);
        gate_acc += fminf(1.f, __expf(lse_real - lse_all));
#pragma unroll
        for (int c = 0; c < 3; c++) {
            int m = t + 256 * c;
            float a = __expf(ll[c] - lse_all);
            sc[m] = a;
            as_l[m] += 0.125f * a;
        }
        __syncthreads();
        int d = t & 15, gI = t >> 4;
        float p = 0.f;
        int mbase = gI * 48;
        for (int i = 0; i < 48; i++) {
            int m = mbase + i;
            p += sc[m] * v[m * D_ + h * DH_ + d];
        }
        part[t] = p;
        __syncthreads();
        if (t < DH_) {
            float s3 = 0.f;
#pragma unroll
            for (int g2 = 0; g2 < 16; g2++) s3 += part[g2 * 16 + t];
            msg[n * D_ + h * DH_ + t] = s3 + a_null * v_null[h * DH_ + t];
        }
    }
    __syncthreads();
#pragma unroll
    for (int c = 0; c < 3; c++) a_s[n * M_ + t + 256 * c] = as_l[t + 256 * c];
    if (t == 0) gate[n] = gate_acc * 0.125f;
}

// ---- fused outproj + LN + ffn1 + ffn2 + LN, 8 rows per block ----
__global__ __launch_bounds__(256) void k_mlp(const float* __restrict__ h_q,
                                             const float* __restrict__ msg,
                                             const float* __restrict__ Wo, const float* __restrict__ bop,
                                             const float* __restrict__ g_ff, const float* __restrict__ b_ff,
                                             const float* __restrict__ W1, const float* __restrict__ b1,
                                             const float* __restrict__ W2, const float* __restrict__ b2,
                                             const float* __restrict__ g_nq, const float* __restrict__ b_nq,
                                             float* __restrict__ h_out, float* __restrict__ qh_new) {
    int r0 = blockIdx.x * 8;
    int t = threadIdx.x;
    __shared__ float xs[8][D_];
    __shared__ float hm[8][D_];
    __shared__ float tl[8][D_];
    __shared__ float ffh[8][FF_];
    for (int i = t; i < 8 * D_; i += 256) xs[i >> 7][i & 127] = msg[r0 * D_ + i];
    __syncthreads();
    // P1: outproj + residual -> hm
    {
        int g = t >> 7, j = t & 127;
        float acc[4] = {0, 0, 0, 0};
        const float4* Wr = (const float4*)(Wo + j * D_);
        for (int i = 0; i < 32; i++) {
            float4 w = Wr[i];
#pragma unroll
            for (int r = 0; r < 4; r++) {
                float4 x = ((const float4*)xs[4 * g + r])[i];
                acc[r] += w.x * x.x + w.y * x.y + w.z * x.z + w.w * x.w;
            }
        }
        float bb = bop[j];
#pragma unroll
        for (int r = 0; r < 4; r++)
            hm[4 * g + r][j] = h_q[(r0 + 4 * g + r) * D_ + j] + acc[r] + bb;
    }
    __syncthreads();
    // P2: LN(hm) -> tl
    {
        int r = t >> 5, l = t & 31;
        float v0 = hm[r][l], v1 = hm[r][l + 32], v2 = hm[r][l + 64], v3 = hm[r][l + 96];
        float s = v0 + v1 + v2 + v3;
#pragma unroll
        for (int o = 1; o < 32; o <<= 1) s += __shfl_xor(s, o);
        float mu = s * (1.f / 128.f);
        float d0 = v0 - mu, d1 = v1 - mu, d2 = v2 - mu, d3 = v3 - mu;
        float vv = d0 * d0 + d1 * d1 + d2 * d2 + d3 * d3;
#pragma unroll
        for (int o = 1; o < 32; o <<= 1) vv += __shfl_xor(vv, o);
        float inv = rsqrtf(vv * (1.f / 128.f) + 1e-5f);
        tl[r][l] = d0 * inv * g_ff[l] + b_ff[l];
        tl[r][l + 32] = d1 * inv * g_ff[l + 32] + b_ff[l + 32];
        tl[r][l + 64] = d2 * inv * g_ff[l + 64] + b_ff[l + 64];
        tl[r][l + 96] = d3 * inv * g_ff[l + 96] + b_ff[l + 96];
    }
    __syncthreads();
    // P3: ffn1 + silu -> ffh (2 outputs per thread)
    {
        int j0 = t, j1 = t + 256;
        float a0[8] = {0}, a1[8] = {0};
        const float4* Wa = (const float4*)(W1 + j0 * D_);
        const float4* Wb = (const float4*)(W1 + j1 * D_);
        for (int i = 0; i < 32; i++) {
            float4 wa = Wa[i], wb = Wb[i];
#pragma unroll
            for (int r = 0; r < 8; r++) {
                float4 x = ((const float4*)tl[r])[i];
                a0[r] += wa.x * x.x + wa.y * x.y + wa.z * x.z + wa.w * x.w;
                a1[r] += wb.x * x.x + wb.y * x.y + wb.z * x.z + wb.w * x.w;
            }
        }
        float bb0 = b1[j0], bb1 = b1[j1];
#pragma unroll
        for (int r = 0; r < 8; r++) {
            ffh[r][j0] = siluf(a0[r] + bb0);
            ffh[r][j1] = siluf(a1[r] + bb1);
        }
    }
    __syncthreads();
    // P4: ffn2 + residual -> h_out global, hm reused as ho
    {
        int g = t >> 7, j = t & 127;
        float acc[4] = {0, 0, 0, 0};
        const float4* Wr = (const float4*)(W2 + j * FF_);
        for (int i = 0; i < 128; i++) {
            float4 w = Wr[i];
#pragma unroll
            for (int r = 0; r < 4; r++) {
                float4 x = ((const float4*)ffh[4 * g + r])[i];
                acc[r] += w.x * x.x + w.y * x.y + w.z * x.z + w.w * x.w;
            }
        }
        float bb = b2[j];
#pragma unroll
        for (int r = 0; r < 4; r++) {
            float vv = hm[4 * g + r][j] + acc[r] + bb;
            h_out[(r0 + 4 * g + r) * D_ + j] = vv;
            hm[4 * g + r][j] = vv;
        }
    }
    __syncthreads();
    // P5: LN(h_out rows) -> qh_new
    {
        int r = t >> 5, l = t & 31;
        float v0 = hm[r][l], v1 = hm[r][l + 32], v2 = hm[r][l + 64], v3 = hm[r][l + 96];
        float s = v0 + v1 + v2 + v3;
#pragma unroll
        for (int o = 1; o < 32; o <<= 1) s += __shfl_xor(s, o);
        float mu = s * (1.f / 128.f);
        float d0 = v0 - mu, d1 = v1 - mu, d2 = v2 - mu, d3 = v3 - mu;
        float vv = d0 * d0 + d1 * d1 + d2 * d2 + d3 * d3;
#pragma unroll
        for (int o = 1; o < 32; o <<= 1) vv += __shfl_xor(vv, o);
        float inv = rsqrtf(vv * (1.f / 128.f) + 1e-5f);
        int rr = (r0 + r) * D_;
        qh_new[rr + l] = d0 * inv * g_nq[l] + b_nq[l];
        qh_new[rr + l + 32] = d1 * inv * g_nq[l + 32] + b_nq[l + 32];
        qh_new[rr + l + 64] = d2 * inv * g_nq[l + 64] + b_nq[l + 64];
        qh_new[rr + l + 96] = d3 * inv * g_nq[l + 96] + b_nq[l + 96];
    }
}

// ---- edge-MLP layer-1 precompute from transposed We1a, 16 rows per block ----
__global__ __launch_bounds__(256) void k_pre(const float* __restrict__ qh_new,
                                             const float* __restrict__ rh,
                                             const float* __restrict__ We1a,
                                             const float* __restrict__ be1,
                                             float* __restrict__ Aq,
                                             float* __restrict__ Br) {
    int bb = blockIdx.x;               // 0..95
    int half = bb >= 48;
    int r0 = (bb - half * 48) * 16;
    int off = half * 128;
    int t = threadIdx.x;
    int r = t >> 4, jg = t & 15;       // row 0..15, j-group of 8
    __shared__ float xs[16][D_];
    const float* in = (half ? rh : qh_new) + r0 * D_;
    for (int i = t; i < 16 * D_; i += 256) xs[i >> 7][i & 127] = in[i];
    __syncthreads();
    float acc[8] = {0};
    const float* xr = xs[r];
    for (int i = 0; i < 128; i++) {
        float x = xr[i];
        const float4 w0 = *(const float4*)(We1a + (off + i) * D_ + jg * 8);
        const float4 w1 = *(const float4*)(We1a + (off + i) * D_ + jg * 8 + 4);
        acc[0] += w0.x * x; acc[1] += w0.y * x; acc[2] += w0.z * x; acc[3] += w0.w * x;
        acc[4] += w1.x * x; acc[5] += w1.y * x; acc[6] += w1.z * x; acc[7] += w1.w * x;
    }
    float* out = (half ? Br : Aq) + (r0 + r) * D_ + jg * 8;
    if (half) {
        const float4 e0 = *(const float4*)(be1 + jg * 8);
        const float4 e1 = *(const float4*)(be1 + jg * 8 + 4);
        acc[0] += e0.x; acc[1] += e0.y; acc[2] += e0.z; acc[3] += e0.w;
        acc[4] += e1.x; acc[5] += e1.y; acc[6] += e1.z; acc[7] += e1.w;
    }
    *(float4*)(out) = make_float4(acc[0], acc[1], acc[2], acc[3]);
    *(float4*)(out + 4) = make_float4(acc[4], acc[5], acc[6], acc[7]);
}

// ---- pair kernel: p-split across 4 waves, af staged via LDS, <=128 regs ----
__global__ __launch_bounds__(256, 4) void k_pair(const float* __restrict__ x_q,
                                                 const float* __restrict__ x_r,
                                                 const float* __restrict__ Aq,
                                                 const float* __restrict__ Br,
                                                 const float* __restrict__ w1r,
                                                 const float* __restrict__ be2,
                                                 const float* __restrict__ Ws,
                                                 const unsigned short* __restrict__ We2b,
                                                 const float* __restrict__ a_s,
                                                 float* __restrict__ dxp) {
    int n = blockIdx.x;
    int chunk = blockIdx.y;
    int cm = chunk * CM_;
    int t = threadIdx.x;
    int w = t >> 6;        // wave id: owns p-slice [w*32, w*32+32); builds pair group w
    int lane = t & 63;
    int col = lane & 15;
    int kg = lane >> 4;

    __shared__ bf16x8 af_st[4][4][64];   // [group][kt][lane], 16B/lane contiguous
    __shared__ float part_s[4][64];      // [wave][pair-in-64]
    __shared__ float xr_l[CM_ * 3];
    __shared__ float as_l[CM_];
    __shared__ float Aq_l[D_];
    __shared__ float w1r_l[D_];
    __shared__ float2 bw_l[D_];

    for (int i = t; i < CM_ * 3; i += 256) xr_l[i] = x_r[cm * 3 + i];
    if (t < CM_) as_l[t] = a_s[n * M_ + cm + t];
    if (t < D_) {
        Aq_l[t] = Aq[n * D_ + t];
        w1r_l[t] = w1r[t];
        bw_l[t] = make_float2(be2[t], Ws[t]);
    }
    __syncthreads();

    // register-resident B slice for this wave: p in [w*32, w*32+32)
    // fragment: lane (col,kg) holds We2[p=(w*2+q)*16+col][k=kt*32+kg*8 ..+8]
    bf16x8 bfr[2][4];
#pragma unroll
    for (int q2 = 0; q2 < 2; q2++)
#pragma unroll
        for (int kt = 0; kt < 4; kt++)
            bfr[q2][kt] = *reinterpret_cast<const bf16x8*>(We2b + ((w * 2 + q2) * 16 + col) * D_ + kt * 32 + kg * 8);

    // per-lane be2/Ws for this lane's 8 p's: p = (w*2+q)*16 + kg*4 + r
    float2 bwv[2][4];
#pragma unroll
    for (int q2 = 0; q2 < 2; q2++)
#pragma unroll
        for (int r = 0; r < 4; r++)
            bwv[q2][r] = bw_l[(w * 2 + q2) * 16 + kg * 4 + r];

    float xq0 = x_q[n * 3 + 0], xq1 = x_q[n * 3 + 1], xq2 = x_q[n * 3 + 2];
    float dxa = 0.f, dya = 0.f, dza = 0.f;

    for (int it = 0; it < CM_ / 64; it++) {
        int mb = it * 64;
        // step 1: build h1 for own group's pair pm, write af fragments to LDS
        {
            int pm = mb + w * 16 + col;
            float d0 = xq0 - xr_l[pm * 3], d1 = xq1 - xr_l[pm * 3 + 1], d2 = xq2 - xr_l[pm * 3 + 2];
            float radial = d0 * d0 + d1 * d1 + d2 * d2;
#pragma unroll
            for (int kt = 0; kt < 4; kt++) {
                int ob = kt * 32 + kg * 8;
                const float4* brp = reinterpret_cast<const float4*>(Br + (cm + pm) * D_ + ob);
                float4 b0 = brp[0], b1 = brp[1];
                const float4 a0 = *(const float4*)(Aq_l + ob), a1 = *(const float4*)(Aq_l + ob + 4);
                const float4 w0 = *(const float4*)(w1r_l + ob), w1 = *(const float4*)(w1r_l + ob + 4);
                bf16x8 af;
                af[0] = f2bf_rn(siluf(a0.x + b0.x + radial * w0.x));
                af[1] = f2bf_rn(siluf(a0.y + b0.y + radial * w0.y));
                af[2] = f2bf_rn(siluf(a0.z + b0.z + radial * w0.z));
                af[3] = f2bf_rn(siluf(a0.w + b0.w + radial * w0.w));
                af[4] = f2bf_rn(siluf(a1.x + b1.x + radial * w1.x));
                af[5] = f2bf_rn(siluf(a1.y + b1.y + radial * w1.y));
                af[6] = f2bf_rn(siluf(a1.z + b1.z + radial * w1.z));
                af[7] = f2bf_rn(siluf(a1.w + b1.w + radial * w1.w));
                af_st[w][kt][lane] = af;
            }
        }
        __syncthreads();   // A: af ready for all groups
        // step 3: MFMA all 4 groups against own 32-p B slice; D[p][pair]
        float sg[4];
#pragma unroll
        for (int g = 0; g < 4; g++) {
            f32x4 acc0 = {0.f, 0.f, 0.f, 0.f}, acc1 = {0.f, 0.f, 0.f, 0.f};
#pragma unroll
            for (int kt = 0; kt < 4; kt++) {
                bf16x8 a = af_st[g][kt][lane];
                acc0 = __builtin_amdgcn_mfma_f32_16x16x32_bf16(bfr[0][kt], a, acc0, 0, 0, 0);
                acc1 = __builtin_amdgcn_mfma_f32_16x16x32_bf16(bfr[1][kt], a, acc1, 0, 0, 0);
            }
            float sv = 0.f;
#pragma unroll
            for (int r = 0; r < 4; r++) {
                sv += siluf(acc0[r] + bwv[0][r].x) * bwv[0][r].y;
                sv += siluf(acc1[r] + bwv[1][r].x) * bwv[1][r].y;
            }
            // reduce over kg (p spans kg*4+r): butterfly over lane bits 4,5
            sv += __shfl_xor(sv, 16);
            sv += __shfl_xor(sv, 32);
            sg[g] = sv;   // partial s for pair g*16+col over this wave's 32 p's
        }
        if (lane < 16) {
#pragma unroll
            for (int g = 0; g < 4; g++) part_s[w][g * 16 + lane] = sg[g];
        }
        __syncthreads();   // B: part_s complete
        // step 5: wave 0 finalizes s for the 64 pairs, accumulates dx
        if (t < 64) {
            float s = part_s[0][t] + part_s[1][t] + part_s[2][t] + part_s[3][t];
            int m2 = mb + t;
            float sw = s * as_l[m2];
            float e0 = xq0 - xr_l[m2 * 3], e1 = xq1 - xr_l[m2 * 3 + 1], e2 = xq2 - xr_l[m2 * 3 + 2];
            float ir = rsqrtf(e0 * e0 + e1 * e1 + e2 * e2 + 1e-8f);
            dxa += e0 * ir * sw;
            dya += e1 * ir * sw;
            dza += e2 * ir * sw;
        }
        // next iter's barrier A protects part_s reads vs. future writes
    }
    if (t < 64) {
#pragma unroll
        for (int o = 1; o < 64; o <<= 1) {
            dxa += __shfl_xor(dxa, o);
            dya += __shfl_xor(dya, o);
            dza += __shfl_xor(dza, o);
        }
        if (t == 0) {
            float* o = dxp + (chunk * N_ + n) * 3;
            o[0] = dxa; o[1] = dya; o[2] = dza;
        }
    }
}

// ---- finalize ----
__global__ __launch_bounds__(256) void k_fin(const float* __restrict__ x_q,
                                             const float* __restrict__ dxp,
                                             const float* __restrict__ gate,
                                             float* __restrict__ x_out) {
    int i = blockIdx.x * 256 + threadIdx.x;
    if (i >= N_ * 3) return;
    int n = i / 3;
    float s = 0.f;
#pragma unroll
    for (int ch = 0; ch < CH_; ch++) s += dxp[(ch * N_ + n) * 3 + (i - n * 3)];
    x_out[i] = x_q[i] + s * gate[n];
}

extern "C" void kernel_launch(void* const* d_in, const int* in_sizes, int n_in,
                              void* d_out, int out_size, void* d_ws, size_t ws_size,
                              hipStream_t stream) {
    const float* h_q   = (const float*)d_in[0];
    const float* x_q   = (const float*)d_in[1];
    const float* h_r   = (const float*)d_in[2];
    const float* x_r   = (const float*)d_in[3];
    const float* Wq    = (const float*)d_in[6];
    const float* bqp   = (const float*)d_in[7];
    const float* Wk    = (const float*)d_in[8];
    const float* bkp   = (const float*)d_in[9];
    const float* Wv    = (const float*)d_in[10];
    const float* bvp   = (const float*)d_in[11];
    const float* Wo    = (const float*)d_in[12];
    const float* bop   = (const float*)d_in[13];
    const float* g_nq  = (const float*)d_in[14];
    const float* b_nq  = (const float*)d_in[15];
    const float* g_nr  = (const float*)d_in[16];
    const float* b_nr  = (const float*)d_in[17];
    const float* g_ff  = (const float*)d_in[18];
    const float* b_ff  = (const float*)d_in[19];
    const float* W1    = (const float*)d_in[20];
    const float* b1    = (const float*)d_in[21];
    const float* W2    = (const float*)d_in[22];
    const float* b2    = (const float*)d_in[23];
    const float* k_null= (const float*)d_in[24];
    const float* v_null= (const float*)d_in[25];
    const float* b_null= (const float*)d_in[26];
    const float* We1   = (const float*)d_in[27];
    const float* be1   = (const float*)d_in[28];
    const float* We2   = (const float*)d_in[29];
    const float* be2   = (const float*)d_in[30];
    const float* Ws    = (const float*)d_in[31];

    float* ws     = (float*)d_ws;
    float* qh     = ws;                   // N*D
    float* rh     = qh + N_ * D_;         // M*D
    float* q      = rh + M_ * D_;         // N*D
    float* k      = q + N_ * D_;          // M*D
    float* v      = k + M_ * D_;          // M*D
    float* a_s    = v + M_ * D_;          // N*M
    float* gate   = a_s + N_ * M_;        // N
    float* msg    = gate + N_;            // N*D
    float* qh_new = msg + N_ * D_;        // N*D
    float* Aq     = qh_new + N_ * D_;     // N*D
    float* Br     = Aq + N_ * D_;         // M*D
    float* We1a   = Br + M_ * D_;         // 257*128 (row 256 = w1r)
    float* dxp    = We1a + 257 * D_;      // CH*N*3
    unsigned short* We2b = (unsigned short*)(dxp + CH_ * N_ * 3);  // D*D bf16
    float* w1r    = We1a + 256 * D_;

    float* h_out = (float*)d_out;         // N*D
    float* x_out = h_out + N_ * D_;       // N*3

    k_ln2<<<N_ + M_, 64, 0, stream>>>(h_q, h_r, g_nq, b_nq, g_nr, b_nr, qh, rh, We2, We2b, We1, We1a);
    k_qkv<<<dim3(96, 3), 128, 0, stream>>>(qh, rh, h_r, Wq, bqp, Wk, bkp, Wv, bvp, q, k, v);
    k_attn<<<N_, 256, 0, stream>>>(q, k, v, k_null, v_null, b_null, a_s, gate, msg);
    k_mlp<<<96, 256, 0, stream>>>(h_q, msg, Wo, bop, g_ff, b_ff, W1, b1, W2, b2, g_nq, b_nq, h_out, qh_new);
    k_pre<<<96, 256, 0, stream>>>(qh_new, rh, We1a, be1, Aq, Br);
    k_pair<<<dim3(N_, CH_), 256, 0, stream>>>(x_q, x_r, Aq, Br, w1r, be2, Ws, We2b, a_s, dxp);
    k_fin<<<9, 256, 0, stream>>>(x_q, dxp, gate, x_out);
}

// Round 5
// 162.963 us; speedup vs baseline: 2.2253x; 1.2337x over previous
//
#include <hip/hip_runtime.h>
#include <hip/hip_bf16.h>
#include <math.h>

#define N_ 768
#define M_ 768
#define D_ 128
#define H_ 8
#define DH_ 16
#define FF_ 512
#define CH_ 4
#define CM_ 192   // M_/CH_

typedef float f32x4 __attribute__((ext_vector_type(4)));
typedef short bf16x8 __attribute__((ext_vector_type(8)));
typedef unsigned short u16x8 __attribute__((ext_vector_type(8)));

__device__ __forceinline__ float siluf(float x) {
    return x * __builtin_amdgcn_rcpf(1.0f + __expf(-x));
}

__device__ __forceinline__ unsigned short f2bf(float x) {
    unsigned int u = __float_as_uint(x);
    unsigned int r = (u + 0x7fffu + ((u >> 16) & 1u)) >> 16;
    return (unsigned short)r;
}

__device__ __forceinline__ short f2bf_rn(float x) {
    __hip_bfloat16 b = __float2bfloat16(x);
    return (short)*reinterpret_cast<unsigned short*>(&b);
}

__device__ __forceinline__ float bf2f(unsigned short u) {
    return __uint_as_float(((unsigned int)u) << 16);
}

// ---- LN for qh & rh rows + We2->bf16 cvt + We1 transpose (folded prep) ----
__global__ __launch_bounds__(64) void k_ln2(const float* __restrict__ h_q,
                                            const float* __restrict__ h_r,
                                            const float* __restrict__ g_nq, const float* __restrict__ b_nq,
                                            const float* __restrict__ g_nr, const float* __restrict__ b_nr,
                                            float* __restrict__ qh, float* __restrict__ rh,
                                            const float* __restrict__ We2, unsigned short* __restrict__ We2b,
                                            const float* __restrict__ We1, float* __restrict__ We1a) {
    int row = blockIdx.x, lane = threadIdx.x;
    const float *src, *g, *b; float* dst;
    if (row < N_) { src = h_q + row * D_; g = g_nq; b = b_nq; dst = qh + row * D_; }
    else { src = h_r + (row - N_) * D_; g = g_nr; b = b_nr; dst = rh + (row - N_) * D_; }
    float x0 = src[lane], x1 = src[lane + 64];
    float s = x0 + x1;
#pragma unroll
    for (int o = 32; o > 0; o >>= 1) s += __shfl_xor(s, o);
    float mu = s * (1.f / 128.f);
    float d0 = x0 - mu, d1 = x1 - mu;
    float v2 = d0 * d0 + d1 * d1;
#pragma unroll
    for (int o = 32; o > 0; o >>= 1) v2 += __shfl_xor(v2, o);
    float inv = rsqrtf(v2 * (1.f / 128.f) + 1e-5f);
    dst[lane] = d0 * inv * g[lane] + b[lane];
    dst[lane + 64] = d1 * inv * g[lane + 64] + b[lane + 64];
    if (row < D_) {
        We2b[row * D_ + lane] = f2bf(We2[row * D_ + lane]);
        We2b[row * D_ + lane + 64] = f2bf(We2[row * D_ + lane + 64]);
    }
    if (row <= 256) {
        We1a[row * D_ + lane] = We1[lane * 257 + row];
        We1a[row * D_ + lane + 64] = We1[(lane + 64) * 257 + row];
    }
}

// ---- q/k/v projections, 8 rows per block; k,v emitted as bf16 ----
__global__ __launch_bounds__(128) void k_qkv(const float* __restrict__ qh,
                                             const float* __restrict__ rh,
                                             const float* __restrict__ h_r,
                                             const float* __restrict__ Wq, const float* __restrict__ bq,
                                             const float* __restrict__ Wk, const float* __restrict__ bk,
                                             const float* __restrict__ Wv, const float* __restrict__ bv,
                                             float* __restrict__ q,
                                             unsigned short* __restrict__ kb,
                                             unsigned short* __restrict__ vb) {
    int r0 = blockIdx.x * 8, which = blockIdx.y, j = threadIdx.x;
    const float* in; const float* W; const float* b;
    if (which == 0) { in = qh; W = Wq; b = bq; }
    else if (which == 1) { in = rh; W = Wk; b = bk; }
    else { in = h_r; W = Wv; b = bv; }
    __shared__ float xs[8][D_];
    for (int i = j; i < 8 * D_; i += 128) xs[i >> 7][i & 127] = in[r0 * D_ + i];
    __syncthreads();
    const float4* Wr = (const float4*)(W + j * D_);
    float acc[8] = {0, 0, 0, 0, 0, 0, 0, 0};
    for (int i = 0; i < 32; i++) {
        float4 w = Wr[i];
#pragma unroll
        for (int r = 0; r < 8; r++) {
            float4 x = ((const float4*)xs[r])[i];
            acc[r] += w.x * x.x + w.y * x.y + w.z * x.z + w.w * x.w;
        }
    }
    float bb = b[j];
    if (which == 0) {
#pragma unroll
        for (int r = 0; r < 8; r++) q[(r0 + r) * D_ + j] = acc[r] + bb;
    } else {
        unsigned short* outb = (which == 1) ? kb : vb;
#pragma unroll
        for (int r = 0; r < 8; r++) outb[(r0 + r) * D_ + j] = (unsigned short)f2bf_rn(acc[r] + bb);
    }
}

// ---- attention v2: one wave per (n, head); bf16 K/V; one barrier ----
__global__ __launch_bounds__(512) void k_attn(const float* __restrict__ q,
                                              const unsigned short* __restrict__ kb,
                                              const unsigned short* __restrict__ vb,
                                              const float* __restrict__ k_null,
                                              const float* __restrict__ v_null,
                                              const float* __restrict__ b_null,
                                              float* __restrict__ a_s,
                                              float* __restrict__ gate,
                                              float* __restrict__ msg) {
    int n = blockIdx.x, t = threadIdx.x;
    int h = t >> 6, lane = t & 63;
    __shared__ float ew[H_][M_];     // per-head a_real rows (24 KB)
    __shared__ float gate_p[H_];
    const float inv = 0.25f;

    // q slice: wave-uniform -> scalar loads
    float qr[DH_];
    const float* qp = q + n * D_ + h * DH_;
#pragma unroll
    for (int d = 0; d < DH_; d++) qr[d] = qp[d];

    // logits for this wave's 12 m's
    float ll[12];
    float lmax = -3.4e38f;
#pragma unroll
    for (int i = 0; i < 12; i++) {
        int m = lane + 64 * i;
        const unsigned short* kp = kb + m * D_ + h * DH_;
        u16x8 k0 = *(const u16x8*)kp;
        u16x8 k1 = *(const u16x8*)(kp + 8);
        float acc = 0.f;
#pragma unroll
        for (int d = 0; d < 8; d++) acc += qr[d] * bf2f(k0[d]);
#pragma unroll
        for (int d = 0; d < 8; d++) acc += qr[d + 8] * bf2f(k1[d]);
        acc *= inv;
        ll[i] = acc;
        lmax = fmaxf(lmax, acc);
    }
#pragma unroll
    for (int o = 32; o > 0; o >>= 1) lmax = fmaxf(lmax, __shfl_xor(lmax, o));
    float es = 0.f;
#pragma unroll
    for (int i = 0; i < 12; i++) es += __expf(ll[i] - lmax);
#pragma unroll
    for (int o = 32; o > 0; o >>= 1) es += __shfl_xor(es, o);

    float lnull;
    {
        const float* kp = k_null + h * DH_;
        float acc = 0.f;
#pragma unroll
        for (int d = 0; d < DH_; d++) acc += qr[d] * kp[d];
        lnull = acc * inv + b_null[h];
    }
    float lse_real = lmax + __logf(es + 1e-9f);
    float m2 = fmaxf(lse_real, lnull);
    float lse_all = m2 + __logf(__expf(lse_real - m2) + __expf(lnull - m2));
    float a_null = __expf(lnull - lse_all);
    if (lane == 0) gate_p[h] = fminf(1.f, __expf(lse_real - lse_all));

    // a_real -> LDS row (own row, same-wave use only before barrier)
#pragma unroll
    for (int i = 0; i < 12; i++) ew[h][lane + 64 * i] = __expf(ll[i] - lse_all);

    // PV cooperative within wave: lane = (d, sub); interleaved m-chunks
    int d = lane & 15, sub = lane >> 4;
    float p = 0.f;
    const f32x4* ewv = (const f32x4*)&ew[h][0];
#pragma unroll 4
    for (int i = 0; i < 48; i++) {
        int m0 = i * 16 + sub * 4;
        f32x4 a4 = ewv[i * 4 + sub];
        const unsigned short* vp = vb + m0 * D_ + h * DH_ + d;
        p += a4[0] * bf2f(vp[0]);
        p += a4[1] * bf2f(vp[D_]);
        p += a4[2] * bf2f(vp[2 * D_]);
        p += a4[3] * bf2f(vp[3 * D_]);
    }
    p += __shfl_xor(p, 16);
    p += __shfl_xor(p, 32);
    if (lane < 16) msg[n * D_ + h * DH_ + lane] = p + a_null * v_null[h * DH_ + lane];

    __syncthreads();
    // a_s = mean over heads; gate
    for (int m = t; m < M_; m += 512) {
        float s = 0.f;
#pragma unroll
        for (int hh = 0; hh < H_; hh++) s += ew[hh][m];
        a_s[n * M_ + m] = s * 0.125f;
    }
    if (t == 0) {
        float s = 0.f;
#pragma unroll
        for (int hh = 0; hh < H_; hh++) s += gate_p[hh];
        gate[n] = s * 0.125f;
    }
}

// ---- fused outproj + LN + ffn1 + ffn2 + LN, 8 rows per block ----
__global__ __launch_bounds__(256) void k_mlp(const float* __restrict__ h_q,
                                             const float* __restrict__ msg,
                                             const float* __restrict__ Wo, const float* __restrict__ bop,
                                             const float* __restrict__ g_ff, const float* __restrict__ b_ff,
                                             const float* __restrict__ W1, const float* __restrict__ b1,
                                             const float* __restrict__ W2, const float* __restrict__ b2,
                                             const float* __restrict__ g_nq, const float* __restrict__ b_nq,
                                             float* __restrict__ h_out, float* __restrict__ qh_new) {
    int r0 = blockIdx.x * 8;
    int t = threadIdx.x;
    __shared__ float xs[8][D_];
    __shared__ float hm[8][D_];
    __shared__ float tl[8][D_];
    __shared__ float ffh[8][FF_];
    for (int i = t; i < 8 * D_; i += 256) xs[i >> 7][i & 127] = msg[r0 * D_ + i];
    __syncthreads();
    {
        int g = t >> 7, j = t & 127;
        float acc[4] = {0, 0, 0, 0};
        const float4* Wr = (const float4*)(Wo + j * D_);
        for (int i = 0; i < 32; i++) {
            float4 w = Wr[i];
#pragma unroll
            for (int r = 0; r < 4; r++) {
                float4 x = ((const float4*)xs[4 * g + r])[i];
                acc[r] += w.x * x.x + w.y * x.y + w.z * x.z + w.w * x.w;
            }
        }
        float bb = bop[j];
#pragma unroll
        for (int r = 0; r < 4; r++)
            hm[4 * g + r][j] = h_q[(r0 + 4 * g + r) * D_ + j] + acc[r] + bb;
    }
    __syncthreads();
    {
        int r = t >> 5, l = t & 31;
        float v0 = hm[r][l], v1 = hm[r][l + 32], v2 = hm[r][l + 64], v3 = hm[r][l + 96];
        float s = v0 + v1 + v2 + v3;
#pragma unroll
        for (int o = 1; o < 32; o <<= 1) s += __shfl_xor(s, o);
        float mu = s * (1.f / 128.f);
        float d0 = v0 - mu, d1 = v1 - mu, d2 = v2 - mu, d3 = v3 - mu;
        float vv = d0 * d0 + d1 * d1 + d2 * d2 + d3 * d3;
#pragma unroll
        for (int o = 1; o < 32; o <<= 1) vv += __shfl_xor(vv, o);
        float inv = rsqrtf(vv * (1.f / 128.f) + 1e-5f);
        tl[r][l] = d0 * inv * g_ff[l] + b_ff[l];
        tl[r][l + 32] = d1 * inv * g_ff[l + 32] + b_ff[l + 32];
        tl[r][l + 64] = d2 * inv * g_ff[l + 64] + b_ff[l + 64];
        tl[r][l + 96] = d3 * inv * g_ff[l + 96] + b_ff[l + 96];
    }
    __syncthreads();
    {
        int j0 = t, j1 = t + 256;
        float a0[8] = {0}, a1[8] = {0};
        const float4* Wa = (const float4*)(W1 + j0 * D_);
        const float4* Wb = (const float4*)(W1 + j1 * D_);
        for (int i = 0; i < 32; i++) {
            float4 wa = Wa[i], wb = Wb[i];
#pragma unroll
            for (int r = 0; r < 8; r++) {
                float4 x = ((const float4*)tl[r])[i];
                a0[r] += wa.x * x.x + wa.y * x.y + wa.z * x.z + wa.w * x.w;
                a1[r] += wb.x * x.x + wb.y * x.y + wb.z * x.z + wb.w * x.w;
            }
        }
        float bb0 = b1[j0], bb1 = b1[j1];
#pragma unroll
        for (int r = 0; r < 8; r++) {
            ffh[r][j0] = siluf(a0[r] + bb0);
            ffh[r][j1] = siluf(a1[r] + bb1);
        }
    }
    __syncthreads();
    {
        int g = t >> 7, j = t & 127;
        float acc[4] = {0, 0, 0, 0};
        const float4* Wr = (const float4*)(W2 + j * FF_);
        for (int i = 0; i < 128; i++) {
            float4 w = Wr[i];
#pragma unroll
            for (int r = 0; r < 4; r++) {
                float4 x = ((const float4*)ffh[4 * g + r])[i];
                acc[r] += w.x * x.x + w.y * x.y + w.z * x.z + w.w * x.w;
            }
        }
        float bb = b2[j];
#pragma unroll
        for (int r = 0; r < 4; r++) {
            float vv = hm[4 * g + r][j] + acc[r] + bb;
            h_out[(r0 + 4 * g + r) * D_ + j] = vv;
            hm[4 * g + r][j] = vv;
        }
    }
    __syncthreads();
    {
        int r = t >> 5, l = t & 31;
        float v0 = hm[r][l], v1 = hm[r][l + 32], v2 = hm[r][l + 64], v3 = hm[r][l + 96];
        float s = v0 + v1 + v2 + v3;
#pragma unroll
        for (int o = 1; o < 32; o <<= 1) s += __shfl_xor(s, o);
        float mu = s * (1.f / 128.f);
        float d0 = v0 - mu, d1 = v1 - mu, d2 = v2 - mu, d3 = v3 - mu;
        float vv = d0 * d0 + d1 * d1 + d2 * d2 + d3 * d3;
#pragma unroll
        for (int o = 1; o < 32; o <<= 1) vv += __shfl_xor(vv, o);
        float inv = rsqrtf(vv * (1.f / 128.f) + 1e-5f);
        int rr = (r0 + r) * D_;
        qh_new[rr + l] = d0 * inv * g_nq[l] + b_nq[l];
        qh_new[rr + l + 32] = d1 * inv * g_nq[l + 32] + b_nq[l + 32];
        qh_new[rr + l + 64] = d2 * inv * g_nq[l + 64] + b_nq[l + 64];
        qh_new[rr + l + 96] = d3 * inv * g_nq[l + 96] + b_nq[l + 96];
    }
}

// ---- edge-MLP layer-1 precompute from transposed We1a, 16 rows per block ----
__global__ __launch_bounds__(256) void k_pre(const float* __restrict__ qh_new,
                                             const float* __restrict__ rh,
                                             const float* __restrict__ We1a,
                                             const float* __restrict__ be1,
                                             float* __restrict__ Aq,
                                             float* __restrict__ Br) {
    int bb = blockIdx.x;
    int half = bb >= 48;
    int r0 = (bb - half * 48) * 16;
    int off = half * 128;
    int t = threadIdx.x;
    int r = t >> 4, jg = t & 15;
    __shared__ float xs[16][D_];
    const float* in = (half ? rh : qh_new) + r0 * D_;
    for (int i = t; i < 16 * D_; i += 256) xs[i >> 7][i & 127] = in[i];
    __syncthreads();
    float acc[8] = {0};
    const float* xr = xs[r];
    for (int i = 0; i < 128; i++) {
        float x = xr[i];
        const float4 w0 = *(const float4*)(We1a + (off + i) * D_ + jg * 8);
        const float4 w1 = *(const float4*)(We1a + (off + i) * D_ + jg * 8 + 4);
        acc[0] += w0.x * x; acc[1] += w0.y * x; acc[2] += w0.z * x; acc[3] += w0.w * x;
        acc[4] += w1.x * x; acc[5] += w1.y * x; acc[6] += w1.z * x; acc[7] += w1.w * x;
    }
    float* out = (half ? Br : Aq) + (r0 + r) * D_ + jg * 8;
    if (half) {
        const float4 e0 = *(const float4*)(be1 + jg * 8);
        const float4 e1 = *(const float4*)(be1 + jg * 8 + 4);
        acc[0] += e0.x; acc[1] += e0.y; acc[2] += e0.z; acc[3] += e0.w;
        acc[4] += e1.x; acc[5] += e1.y; acc[6] += e1.z; acc[7] += e1.w;
    }
    *(float4*)(out) = make_float4(acc[0], acc[1], acc[2], acc[3]);
    *(float4*)(out + 4) = make_float4(acc[4], acc[5], acc[6], acc[7]);
}

// ---- pair kernel: p-split across 4 waves, af staged via LDS, <=128 regs ----
__global__ __launch_bounds__(256, 4) void k_pair(const float* __restrict__ x_q,
                                                 const float* __restrict__ x_r,
                                                 const float* __restrict__ Aq,
                                                 const float* __restrict__ Br,
                                                 const float* __restrict__ w1r,
                                                 const float* __restrict__ be2,
                                                 const float* __restrict__ Ws,
                                                 const unsigned short* __restrict__ We2b,
                                                 const float* __restrict__ a_s,
                                                 float* __restrict__ dxp) {
    int n = blockIdx.x;
    int chunk = blockIdx.y;
    int cm = chunk * CM_;
    int t = threadIdx.x;
    int w = t >> 6;
    int lane = t & 63;
    int col = lane & 15;
    int kg = lane >> 4;

    __shared__ bf16x8 af_st[4][4][64];
    __shared__ float part_s[4][64];
    __shared__ float xr_l[CM_ * 3];
    __shared__ float as_l[CM_];
    __shared__ float Aq_l[D_];
    __shared__ float w1r_l[D_];
    __shared__ float2 bw_l[D_];

    for (int i = t; i < CM_ * 3; i += 256) xr_l[i] = x_r[cm * 3 + i];
    if (t < CM_) as_l[t] = a_s[n * M_ + cm + t];
    if (t < D_) {
        Aq_l[t] = Aq[n * D_ + t];
        w1r_l[t] = w1r[t];
        bw_l[t] = make_float2(be2[t], Ws[t]);
    }
    __syncthreads();

    bf16x8 bfr[2][4];
#pragma unroll
    for (int q2 = 0; q2 < 2; q2++)
#pragma unroll
        for (int kt = 0; kt < 4; kt++)
            bfr[q2][kt] = *reinterpret_cast<const bf16x8*>(We2b + ((w * 2 + q2) * 16 + col) * D_ + kt * 32 + kg * 8);

    float2 bwv[2][4];
#pragma unroll
    for (int q2 = 0; q2 < 2; q2++)
#pragma unroll
        for (int r = 0; r < 4; r++)
            bwv[q2][r] = bw_l[(w * 2 + q2) * 16 + kg * 4 + r];

    float xq0 = x_q[n * 3 + 0], xq1 = x_q[n * 3 + 1], xq2 = x_q[n * 3 + 2];
    float dxa = 0.f, dya = 0.f, dza = 0.f;

    for (int it = 0; it < CM_ / 64; it++) {
        int mb = it * 64;
        {
            int pm = mb + w * 16 + col;
            float d0 = xq0 - xr_l[pm * 3], d1 = xq1 - xr_l[pm * 3 + 1], d2 = xq2 - xr_l[pm * 3 + 2];
            float radial = d0 * d0 + d1 * d1 + d2 * d2;
#pragma unroll
            for (int kt = 0; kt < 4; kt++) {
                int ob = kt * 32 + kg * 8;
                const float4* brp = reinterpret_cast<const float4*>(Br + (cm + pm) * D_ + ob);
                float4 b0 = brp[0], b1 = brp[1];
                const float4 a0 = *(const float4*)(Aq_l + ob), a1 = *(const float4*)(Aq_l + ob + 4);
                const float4 w0 = *(const float4*)(w1r_l + ob), w1 = *(const float4*)(w1r_l + ob + 4);
                bf16x8 af;
                af[0] = f2bf_rn(siluf(a0.x + b0.x + radial * w0.x));
                af[1] = f2bf_rn(siluf(a0.y + b0.y + radial * w0.y));
                af[2] = f2bf_rn(siluf(a0.z + b0.z + radial * w0.z));
                af[3] = f2bf_rn(siluf(a0.w + b0.w + radial * w0.w));
                af[4] = f2bf_rn(siluf(a1.x + b1.x + radial * w1.x));
                af[5] = f2bf_rn(siluf(a1.y + b1.y + radial * w1.y));
                af[6] = f2bf_rn(siluf(a1.z + b1.z + radial * w1.z));
                af[7] = f2bf_rn(siluf(a1.w + b1.w + radial * w1.w));
                af_st[w][kt][lane] = af;
            }
        }
        __syncthreads();
        float sg[4];
#pragma unroll
        for (int g = 0; g < 4; g++) {
            f32x4 acc0 = {0.f, 0.f, 0.f, 0.f}, acc1 = {0.f, 0.f, 0.f, 0.f};
#pragma unroll
            for (int kt = 0; kt < 4; kt++) {
                bf16x8 a = af_st[g][kt][lane];
                acc0 = __builtin_amdgcn_mfma_f32_16x16x32_bf16(bfr[0][kt], a, acc0, 0, 0, 0);
                acc1 = __builtin_amdgcn_mfma_f32_16x16x32_bf16(bfr[1][kt], a, acc1, 0, 0, 0);
            }
            float sv = 0.f;
#pragma unroll
            for (int r = 0; r < 4; r++) {
                sv += siluf(acc0[r] + bwv[0][r].x) * bwv[0][r].y;
                sv += siluf(acc1[r] + bwv[1][r].x) * bwv[1][r].y;
            }
            sv += __shfl_xor(sv, 16);
            sv += __shfl_xor(sv, 32);
            sg[g] = sv;
        }
        if (lane < 16) {
#pragma unroll
            for (int g = 0; g < 4; g++) part_s[w][g * 16 + lane] = sg[g];
        }
        __syncthreads();
        if (t < 64) {
            float s = part_s[0][t] + part_s[1][t] + part_s[2][t] + part_s[3][t];
            int m2 = mb + t;
            float sw = s * as_l[m2];
            float e0 = xq0 - xr_l[m2 * 3], e1 = xq1 - xr_l[m2 * 3 + 1], e2 = xq2 - xr_l[m2 * 3 + 2];
            float ir = rsqrtf(e0 * e0 + e1 * e1 + e2 * e2 + 1e-8f);
            dxa += e0 * ir * sw;
            dya += e1 * ir * sw;
            dza += e2 * ir * sw;
        }
    }
    if (t < 64) {
#pragma unroll
        for (int o = 1; o < 64; o <<= 1) {
            dxa += __shfl_xor(dxa, o);
            dya += __shfl_xor(dya, o);
            dza += __shfl_xor(dza, o);
        }
        if (t == 0) {
            float* o = dxp + (chunk * N_ + n) * 3;
            o[0] = dxa; o[1] = dya; o[2] = dza;
        }
    }
}

// ---- finalize ----
__global__ __launch_bounds__(256) void k_fin(const float* __restrict__ x_q,
                                             const float* __restrict__ dxp,
                                             const float* __restrict__ gate,
                                             float* __restrict__ x_out) {
    int i = blockIdx.x * 256 + threadIdx.x;
    if (i >= N_ * 3) return;
    int n = i / 3;
    float s = 0.f;
#pragma unroll
    for (int ch = 0; ch < CH_; ch++) s += dxp[(ch * N_ + n) * 3 + (i - n * 3)];
    x_out[i] = x_q[i] + s * gate[n];
}

extern "C" void kernel_launch(void* const* d_in, const int* in_sizes, int n_in,
                              void* d_out, int out_size, void* d_ws, size_t ws_size,
                              hipStream_t stream) {
    const float* h_q   = (const float*)d_in[0];
    const float* x_q   = (const float*)d_in[1];
    const float* h_r   = (const float*)d_in[2];
    const float* x_r   = (const float*)d_in[3];
    const float* Wq    = (const float*)d_in[6];
    const float* bqp   = (const float*)d_in[7];
    const float* Wk    = (const float*)d_in[8];
    const float* bkp   = (const float*)d_in[9];
    const float* Wv    = (const float*)d_in[10];
    const float* bvp   = (const float*)d_in[11];
    const float* Wo    = (const float*)d_in[12];
    const float* bop   = (const float*)d_in[13];
    const float* g_nq  = (const float*)d_in[14];
    const float* b_nq  = (const float*)d_in[15];
    const float* g_nr  = (const float*)d_in[16];
    const float* b_nr  = (const float*)d_in[17];
    const float* g_ff  = (const float*)d_in[18];
    const float* b_ff  = (const float*)d_in[19];
    const float* W1    = (const float*)d_in[20];
    const float* b1    = (const float*)d_in[21];
    const float* W2    = (const float*)d_in[22];
    const float* b2    = (const float*)d_in[23];
    const float* k_null= (const float*)d_in[24];
    const float* v_null= (const float*)d_in[25];
    const float* b_null= (const float*)d_in[26];
    const float* We1   = (const float*)d_in[27];
    const float* be1   = (const float*)d_in[28];
    const float* We2   = (const float*)d_in[29];
    const float* be2   = (const float*)d_in[30];
    const float* Ws    = (const float*)d_in[31];

    float* ws     = (float*)d_ws;
    float* qh     = ws;                   // N*D
    float* rh     = qh + N_ * D_;         // M*D
    float* q      = rh + M_ * D_;         // N*D
    unsigned short* kb = (unsigned short*)(q + N_ * D_);  // M*D bf16
    unsigned short* vb = kb + M_ * D_;                    // M*D bf16
    float* a_s    = (float*)(vb + M_ * D_);  // N*M
    float* gate   = a_s + N_ * M_;        // N
    float* msg    = gate + N_;            // N*D
    float* qh_new = msg + N_ * D_;        // N*D
    float* Aq     = qh_new + N_ * D_;     // N*D
    float* Br     = Aq + N_ * D_;         // M*D
    float* We1a   = Br + M_ * D_;         // 257*128 (row 256 = w1r)
    float* dxp    = We1a + 257 * D_;      // CH*N*3
    unsigned short* We2b = (unsigned short*)(dxp + CH_ * N_ * 3);  // D*D bf16
    float* w1r    = We1a + 256 * D_;

    float* h_out = (float*)d_out;         // N*D
    float* x_out = h_out + N_ * D_;       // N*3

    k_ln2<<<N_ + M_, 64, 0, stream>>>(h_q, h_r, g_nq, b_nq, g_nr, b_nr, qh, rh, We2, We2b, We1, We1a);
    k_qkv<<<dim3(96, 3), 128, 0, stream>>>(qh, rh, h_r, Wq, bqp, Wk, bkp, Wv, bvp, q, kb, vb);
    k_attn<<<N_, 512, 0, stream>>>(q, kb, vb, k_null, v_null, b_null, a_s, gate, msg);
    k_mlp<<<96, 256, 0, stream>>>(h_q, msg, Wo, bop, g_ff, b_ff, W1, b1, W2, b2, g_nq, b_nq, h_out, qh_new);
    k_pre<<<96, 256, 0, stream>>>(qh_new, rh, We1a, be1, Aq, Br);
    k_pair<<<dim3(N_, CH_), 256, 0, stream>>>(x_q, x_r, Aq, Br, w1r, be2, Ws, We2b, a_s, dxp);
    k_fin<<<9, 256, 0, stream>>>(x_q, dxp, gate, x_out);
}